// Round 7
// baseline (3986.713 us; speedup 1.0000x reference)
//
#include <hip/hip_runtime.h>
#include <hip/hip_bf16.h>
#include <math.h>

#define S_LEN 215
#define NB    512
#define DI    36
#define DMODEL 144
#define DT    160
#define NH    4
#define DH    40
#define NHID  128
#define FIN   860
#define FINP  864          // K-padded
#define DFIN  196
#define TP    232          // LDS t-stride (shorts): 464B rows -> 16B-aligned, 2-way banks
#define CDIV(a,b) (((a)+(b)-1)/(b))

typedef __attribute__((ext_vector_type(8))) short bf16x8;
typedef __attribute__((ext_vector_type(4))) float f32x4;

__device__ inline bf16x8 zz_cvt8(const float* __restrict__ p) {
  float4 lo = *(const float4*)p;
  float4 hi = *(const float4*)(p + 4);
  union { bf16x8 v; __hip_bfloat16 h[8]; } u;
  u.h[0] = __float2bfloat16(lo.x); u.h[1] = __float2bfloat16(lo.y);
  u.h[2] = __float2bfloat16(lo.z); u.h[3] = __float2bfloat16(lo.w);
  u.h[4] = __float2bfloat16(hi.x); u.h[5] = __float2bfloat16(hi.y);
  u.h[6] = __float2bfloat16(hi.z); u.h[7] = __float2bfloat16(hi.w);
  return u.v;
}

__device__ inline bf16x8 zz_cvt8a(const float t[8]) {
  union { bf16x8 v; __hip_bfloat16 h[8]; } u;
  #pragma unroll
  for (int i = 0; i < 8; ++i) u.h[i] = __float2bfloat16(t[i]);
  return u.v;
}

// ---------------- weight transpose + bf16 convert: WT[n][k] = bf16(W[k][n]) ----------------
__global__ __launch_bounds__(256) void zz_wcvt(const float* __restrict__ W,
    short* __restrict__ WT, int K, int N, int Kpad, int Npad)
{
  int idx = blockIdx.x*256 + threadIdx.x;
  if (idx >= Npad*Kpad) return;
  int n = idx / Kpad, k = idx % Kpad;
  float v = (n < N && k < K) ? W[(size_t)k*N + n] : 0.f;
  union { __hip_bfloat16 h; short s; } c;
  c.h = __float2bfloat16(v);
  WT[idx] = c.s;
}

// ---------------- build x chunk ----------------
__global__ __launch_bounds__(256) void zz_build_x(const float* __restrict__ src,
    const float* __restrict__ R_u, float* __restrict__ X, int b0, int CB)
{
  int idx = blockIdx.x*256 + threadIdx.x;           // (bl,i,s)
  if (idx >= CB*DI*S_LEN) return;
  int s = idx % S_LEN; int t = idx / S_LEN; int i = t % DI; int bl = t / DI;
  float v = src[((size_t)s*NB + b0 + bl)*(2*DI) + i];
  float4 r = *(const float4*)(R_u + i*4);
  float4 o;
  o.x = fmaxf(v*r.x, 0.f); o.y = fmaxf(v*r.y, 0.f);
  o.z = fmaxf(v*r.z, 0.f); o.w = fmaxf(v*r.w, 0.f);
  *(float4*)(X + (size_t)(bl*DI + i)*FINP + s*4) = o;
}

// ---------------- zero pad cols 860..863 ----------------
__global__ __launch_bounds__(256) void zz_zeropad(float* __restrict__ buf, int CB)
{
  int idx = blockIdx.x*256 + threadIdx.x;
  if (idx >= CB*DI) return;
  float4 z = {0.f,0.f,0.f,0.f};
  *(float4*)(buf + (size_t)idx*FINP + FIN) = z;
}

// ---------------- positional encoding ----------------
__global__ __launch_bounds__(256) void zz_pe(const float* __restrict__ times,
    float* __restrict__ XCH, int b0, int CB)
{
  int idx = blockIdx.x*256 + threadIdx.x;           // (tl, k)
  if (idx >= CB*S_LEN*16) return;
  int k = idx & 15; int tl = idx >> 4;
  int bl = tl % CB; int s = tl / CB;
  int j = k & 7;
  float ts = powf(215.f, (float)j * (1.f/7.f)) * 100.f;
  float sc = times[(size_t)s*NB + b0 + bl] / ts;
  XCH[(size_t)tl*DT + DMODEL + k] = (k < 8) ? sinf(sc) : cosf(sc);
}

// ---------------- emb ----------------
__global__ __launch_bounds__(256) void zz_emb(const float* __restrict__ st,
    const float* __restrict__ w, const float* __restrict__ bias, float* __restrict__ emb)
{
  int idx = blockIdx.x*256 + threadIdx.x;
  if (idx >= NB*DI) return;
  int b = idx / DI, k = idx % DI;
  float acc = bias[k];
  #pragma unroll
  for (int j = 0; j < 9; ++j) acc = fmaf(st[b*9 + j], w[j*DI + k], acc);
  emb[idx] = acc;
}

// ---------------- GAT GEMM via MFMA ----------------
__global__ __launch_bounds__(256) void zz_gat_mfma(const float* __restrict__ X,
    const short* __restrict__ WT, float* __restrict__ XP, int CB)
{
  int bl = blockIdx.y, half = blockIdx.x;
  int wave = threadIdx.x >> 6, lane = threadIdx.x & 63;
  int r = lane & 15, g = lane >> 4;
  const float* Xb = X + (size_t)bl*DI*FINP;
  float* XPb = XP + (size_t)bl*DI*FINP;
  int p0 = half ? 14 : 0, p1 = half ? 27 : 14;
  int ntasks = 3 * (p1 - p0);
  for (int task = wave; task < ntasks; task += 4) {
    int mt = task % 3; int ntp = p0 + task / 3;
    int m0 = mt*16;
    int arow = m0 + r; if (arow > DI-1) arow = DI-1;
    const float* Ap = Xb + (size_t)arow*FINP + g*8;
    int n0 = ntp*32;
    const short* B0 = WT + (size_t)(n0 + r)*FINP + g*8;
    const short* B1 = B0 + (size_t)16*FINP;
    f32x4 acc0 = {0.f,0.f,0.f,0.f}, acc1 = {0.f,0.f,0.f,0.f};
    #pragma unroll 3
    for (int k0 = 0; k0 < FINP; k0 += 32) {
      bf16x8 af = zz_cvt8(Ap + k0);
      bf16x8 b0 = *(const bf16x8*)(B0 + k0);
      bf16x8 b1 = *(const bf16x8*)(B1 + k0);
      acc0 = __builtin_amdgcn_mfma_f32_16x16x32_bf16(af, b0, acc0, 0, 0, 0);
      acc1 = __builtin_amdgcn_mfma_f32_16x16x32_bf16(af, b1, acc1, 0, 0, 0);
    }
    #pragma unroll
    for (int j = 0; j < 4; ++j) {
      int row = m0 + g*4 + j;
      if (row < DI) {
        int c0 = n0 + r, c1 = n0 + 16 + r;
        if (c0 < FIN) XPb[(size_t)row*FINP + c0] = acc0[j];
        if (c1 < FIN) XPb[(size_t)row*FINP + c1] = acc1[j];
      }
    }
  }
}

// ---------------- per-row dots ----------------
__global__ __launch_bounds__(64) void zz_gat_attvec(const float* __restrict__ XP,
    const float* __restrict__ a_s, const float* __restrict__ a_d,
    float* __restrict__ ss, float* __restrict__ sd, int b0)
{
  int i = blockIdx.x, bl = blockIdx.y, lane = threadIdx.x;
  const float* row = XP + ((size_t)bl*DI + i)*FINP;
  float ps = 0.f, pd = 0.f;
  for (int k = lane; k < FIN; k += 64) {
    float v = row[k];
    ps = fmaf(v, a_s[k], ps);
    pd = fmaf(v, a_d[k], pd);
  }
  for (int off = 32; off; off >>= 1) { ps += __shfl_xor(ps, off); pd += __shfl_xor(pd, off); }
  if (!lane) { ss[(b0 + bl)*DI + i] = ps; sd[(b0 + bl)*DI + i] = pd; }
}

// ---------------- alpha softmax ----------------
__global__ __launch_bounds__(256) void zz_gat_alpha(const float* __restrict__ ss,
    const float* __restrict__ sd, const float* __restrict__ edge, float* __restrict__ alpha, int b0)
{
  int b = b0 + blockIdx.x;
  int wv = threadIdx.x >> 6, lane = threadIdx.x & 63;
  for (int i = wv; i < DI; i += 4) {
    float di = sd[b*DI + i];
    float e = -3e38f, x = 0.f;
    if (lane < DI) {
      x = di + ss[b*DI + lane];
      x = (x >= 0.f) ? x : 0.2f*x;
      e = x;
    }
    float m = e;
    for (int off = 32; off; off >>= 1) m = fmaxf(m, __shfl_xor(m, off));
    float p = (lane < DI) ? expf(e - m) : 0.f;
    float s = p;
    for (int off = 32; off; off >>= 1) s += __shfl_xor(s, off);
    if (lane < DI) {
      float a = p / s;
      size_t o = ((size_t)b*DI + i)*DI + lane;
      if (edge) a *= edge[o];
      alpha[o] = a;
    }
  }
}

// ---------------- gat apply ----------------
__global__ __launch_bounds__(256) void zz_gat_apply(const float* __restrict__ alpha,
    const float* __restrict__ XP, float* __restrict__ out, int mode, int b0, int CB)
{
  __shared__ float Al[DI][37];
  __shared__ float Xs[DI][260];
  int bl = blockIdx.y, n0 = blockIdx.x * 256;
  int tid = threadIdx.x;
  int nt = tid & 63, mg = tid >> 6;
  const float* ab = alpha + ((size_t)(b0 + bl))*DI*DI;
  for (int i = tid; i < DI*DI; i += 256) Al[i/DI][i%DI] = ab[i];
  const float* XPb = XP + (size_t)bl*DI*FINP;
  for (int i = tid; i < DI*256; i += 256) {
    int k = i >> 8, nn = i & 255, gn = n0 + nn;
    Xs[k][nn] = (gn < FIN) ? XPb[(size_t)k*FINP + gn] : 0.f;
  }
  __syncthreads();
  float acc[9][4] = {};
  #pragma unroll 4
  for (int k = 0; k < DI; ++k) {
    float4 x4 = *(const float4*)&Xs[k][nt*4];
    float xb[4] = {x4.x, x4.y, x4.z, x4.w};
    #pragma unroll
    for (int m = 0; m < 9; ++m) {
      float av = Al[mg*9 + m][k];
      #pragma unroll
      for (int v = 0; v < 4; ++v) acc[m][v] = fmaf(av, xb[v], acc[m][v]);
    }
  }
  int gn = n0 + nt*4;
  if (gn < FIN) {
    if (mode == 0) {
      float* ob = out + (size_t)bl*DI*FINP;
      #pragma unroll
      for (int m = 0; m < 9; ++m) {
        float4 o4 = {acc[m][0], acc[m][1], acc[m][2], acc[m][3]};
        *(float4*)(ob + (size_t)(mg*9 + m)*FINP + gn) = o4;
      }
    } else {
      int s = gn >> 2;
      float* op = out + ((size_t)s*CB + bl)*DT;
      #pragma unroll
      for (int m = 0; m < 9; ++m) {
        float4 o4 = {acc[m][0], acc[m][1], acc[m][2], acc[m][3]};
        *(float4*)(op + (mg*9 + m)*4) = o4;
      }
    }
  }
}

// ---------------- distance helpers ----------------
__global__ __launch_bounds__(64) void zz_sq(const float* __restrict__ A, float* __restrict__ sq)
{
  int i = blockIdx.x, lane = threadIdx.x;
  const float* row = A + (size_t)i*(DI*DI);
  float s = 0.f;
  for (int k = lane; k < DI*DI; k += 64) { float v = row[k]; s = fmaf(v, v, s); }
  for (int off = 32; off; off >>= 1) s += __shfl_xor(s, off);
  if (!lane) sq[i] = s;
}

__global__ __launch_bounds__(256) void zz_dist(const float* __restrict__ A,
    const float* __restrict__ sq, float* __restrict__ dsum)
{
  __shared__ float Ai[64][65], Aj[64][65];
  __shared__ float red[256];
  int i0 = blockIdx.y*64, j0 = blockIdx.x*64;
  int tid = threadIdx.x, tx = tid % 16, ty = tid / 16;
  float acc[4][4] = {};
  for (int k0 = 0; k0 < DI*DI; k0 += 64) {
    for (int t = tid; t < 64*64; t += 256) {
      int r = t >> 6, kk = t & 63, gk = k0 + kk;
      float vi = 0.f, vj = 0.f;
      if (gk < DI*DI) {
        vi = A[(size_t)(i0 + r)*(DI*DI) + gk];
        vj = A[(size_t)(j0 + r)*(DI*DI) + gk];
      }
      Ai[r][kk] = vi; Aj[r][kk] = vj;
    }
    __syncthreads();
    #pragma unroll 8
    for (int kk = 0; kk < 64; ++kk) {
      float a[4], bb[4];
      #pragma unroll
      for (int u = 0; u < 4; ++u) a[u]  = Ai[ty*4 + u][kk];
      #pragma unroll
      for (int u = 0; u < 4; ++u) bb[u] = Aj[tx*4 + u][kk];
      #pragma unroll
      for (int u = 0; u < 4; ++u)
        #pragma unroll
        for (int v = 0; v < 4; ++v) acc[u][v] = fmaf(a[u], bb[v], acc[u][v]);
    }
    __syncthreads();
  }
  float s = 0.f;
  #pragma unroll
  for (int u = 0; u < 4; ++u)
    #pragma unroll
    for (int v = 0; v < 4; ++v) {
      float d2 = sq[i0 + ty*4 + u] + sq[j0 + tx*4 + v] - 2.f*acc[u][v];
      d2 = fmaxf(d2, 0.f);
      s += sqrtf(d2 + 1e-12f);
    }
  red[tid] = s; __syncthreads();
  for (int st = 128; st; st >>= 1) { if (tid < st) red[tid] += red[tid + st]; __syncthreads(); }
  if (!tid) atomicAdd(dsum, red[0]);
}

__global__ void zz_dist_fin(const float* dsum, float* out)
{
  out[0] = dsum[0] * (1.f/((float)NB*(float)NB));
}

// ---------------- token GEMM via MFMA ----------------
template<int RELU, int RES>
__global__ __launch_bounds__(256) void zz_mgemm(const float* __restrict__ A,
    const short* __restrict__ BT, const float* __restrict__ bias,
    const float* __restrict__ res, float* __restrict__ C, int M, int N, int K)
{
  int wave = threadIdx.x >> 6, lane = threadIdx.x & 63;
  int m0 = blockIdx.x*64 + wave*16;
  if (m0 >= M) return;
  int r = lane & 15, g = lane >> 4;
  int arow = m0 + r; if (arow >= M) arow = M - 1;
  const float* Ap = A + (size_t)arow*K + g*8;
  int NP = N >> 5;
  for (int ntp = 0; ntp < NP; ++ntp) {
    int n0 = ntp*32;
    const short* B0 = BT + (size_t)(n0 + r)*K + g*8;
    const short* B1 = B0 + (size_t)16*K;
    f32x4 acc0 = {0.f,0.f,0.f,0.f}, acc1 = {0.f,0.f,0.f,0.f};
    #pragma unroll 5
    for (int k0 = 0; k0 < K; k0 += 32) {
      bf16x8 af = zz_cvt8(Ap + k0);
      bf16x8 b0 = *(const bf16x8*)(B0 + k0);
      bf16x8 b1 = *(const bf16x8*)(B1 + k0);
      acc0 = __builtin_amdgcn_mfma_f32_16x16x32_bf16(af, b0, acc0, 0, 0, 0);
      acc1 = __builtin_amdgcn_mfma_f32_16x16x32_bf16(af, b1, acc1, 0, 0, 0);
    }
    #pragma unroll
    for (int j = 0; j < 4; ++j) {
      int row = m0 + g*4 + j;
      if (row >= M) continue;
      int c0 = n0 + r, c1 = n0 + 16 + r;
      float v0 = acc0[j] + bias[c0];
      float v1 = acc1[j] + bias[c1];
      if (RES) { v0 += res[(size_t)row*N + c0]; v1 += res[(size_t)row*N + c1]; }
      if (RELU) { v0 = fmaxf(v0, 0.f); v1 = fmaxf(v1, 0.f); }
      C[(size_t)row*N + c0] = v0;
      C[(size_t)row*N + c1] = v1;
    }
  }
}

// ---------------- f32 tiled GEMM (head) ----------------
template<int RELU, int RES>
__global__ __launch_bounds__(256) void zz_gemm(const float* __restrict__ A,
    const float* __restrict__ Bw, const float* __restrict__ bias,
    const float* __restrict__ res, float* __restrict__ C, int M, int N, int K)
{
  __shared__ float As[64][33];
  __shared__ float Bs[32][136];
  int m0 = blockIdx.y*64, n0 = blockIdx.x*128;
  int tid = threadIdx.x, tx = tid & 15, ty = tid >> 4;
  float acc[4][8] = {};
  for (int k0 = 0; k0 < K; k0 += 32) {
    for (int i = tid; i < 64*32; i += 256) {
      int rr = i >> 5, kk = i & 31;
      int gm = m0 + rr, gk = k0 + kk;
      As[rr][kk] = (gm < M && gk < K) ? A[(size_t)gm*K + gk] : 0.f;
    }
    for (int i = tid; i < 32*128; i += 256) {
      int kk = i >> 7, n = i & 127;
      int gk = k0 + kk, gn = n0 + n;
      Bs[kk][n] = (gk < K && gn < N) ? Bw[(size_t)gk*N + gn] : 0.f;
    }
    __syncthreads();
    #pragma unroll 4
    for (int kk = 0; kk < 32; ++kk) {
      float a[4];
      #pragma unroll
      for (int u = 0; u < 4; ++u) a[u] = As[ty*4 + u][kk];
      float4 b0 = *(const float4*)&Bs[kk][tx*8];
      float4 b1 = *(const float4*)&Bs[kk][tx*8 + 4];
      float b[8] = {b0.x,b0.y,b0.z,b0.w,b1.x,b1.y,b1.z,b1.w};
      #pragma unroll
      for (int u = 0; u < 4; ++u)
        #pragma unroll
        for (int v = 0; v < 8; ++v) acc[u][v] = fmaf(a[u], b[v], acc[u][v]);
    }
    __syncthreads();
  }
  #pragma unroll
  for (int u = 0; u < 4; ++u) {
    int gm = m0 + ty*4 + u;
    if (gm >= M) continue;
    #pragma unroll
    for (int v = 0; v < 8; ++v) {
      int gn = n0 + tx*8 + v;
      if (gn >= N) continue;
      float val = acc[u][v] + bias[gn];
      if (RES) val += res[(size_t)gm*N + gn];
      if (RELU) val = fmaxf(val, 0.f);
      C[(size_t)gm*N + gn] = val;
    }
  }
}

// ---------------- fused MFMA attention: block=(bl,h), wave = one 16-row Q tile ----------------
// scores = (Q/sqrt40) @ K^T via mfma ; mask ; in-register row softmax ; P->bf16 LDS ; PV via mfma
__global__ __launch_bounds__(256) void zz_fattn(const float* __restrict__ QKV,
    const int* __restrict__ lengths, float* __restrict__ O, int b0, int CB)
{
  __shared__ short VT[64][TP];        // V^T bf16: VT[d][t]
  __shared__ short PT[4][16][TP];     // per-wave P tile bf16: PT[w][row][t]
  const float LOG2E = 1.44269504088896f;
  int bh = blockIdx.x, bl = bh >> 2, h = bh & 3;
  int tid = threadIdx.x, wave = tid >> 6, lane = tid & 63;
  int len = lengths[b0 + bl];
  // phase 0: build V^T in LDS (bf16), zero-padded
  for (int i = tid; i < 224*64; i += 256) {
    int t = i >> 6, d = i & 63;
    float v = 0.f;
    if (t < S_LEN && d < DH) v = QKV[((size_t)t*CB + bl)*(3*DT) + 2*DT + h*DH + d];
    union { __hip_bfloat16 hh; short s; } c; c.hh = __float2bfloat16(v);
    VT[d][t] = c.s;
  }
  __syncthreads();

  int mt = blockIdx.y*4 + wave; if (mt > 13) mt = 13;   // clamp: no divergence
  int m0 = mt*16;
  int r = lane & 15, g = lane >> 4;

  // Q A-frags (2 k-steps of 32 over D=40 padded to 64), scale folded in
  int qrow = m0 + r; if (qrow > S_LEN-1) qrow = S_LEN-1;
  const float* qp = QKV + ((size_t)qrow*CB + bl)*(3*DT) + h*DH;
  bf16x8 qf0, qf1;
  {
    float t0[8], t1[8];
    #pragma unroll
    for (int u = 0; u < 8; ++u) t0[u] = qp[g*8 + u] * 0.15811388300841897f;
    #pragma unroll
    for (int u = 0; u < 8; ++u) t1[u] = (g == 0) ? qp[32 + u] * 0.15811388300841897f : 0.f;
    qf0 = zz_cvt8a(t0); qf1 = zz_cvt8a(t1);
  }

  // QK^T: 14 n-tiles of accumulators
  f32x4 acc[14];
  #pragma unroll
  for (int nt = 0; nt < 14; ++nt) acc[nt] = (f32x4){0.f,0.f,0.f,0.f};
  #pragma unroll
  for (int nt = 0; nt < 14; ++nt) {
    int trow = nt*16 + r; if (trow > S_LEN-1) trow = S_LEN-1;
    const float* kp = QKV + ((size_t)trow*CB + bl)*(3*DT) + DT + h*DH;
    float t0[8], t1[8];
    #pragma unroll
    for (int u = 0; u < 8; ++u) t0[u] = kp[g*8 + u];
    #pragma unroll
    for (int u = 0; u < 8; ++u) t1[u] = (g == 0) ? kp[32 + u] : 0.f;
    acc[nt] = __builtin_amdgcn_mfma_f32_16x16x32_bf16(qf0, zz_cvt8a(t0), acc[nt], 0, 0, 0);
    acc[nt] = __builtin_amdgcn_mfma_f32_16x16x32_bf16(qf1, zz_cvt8a(t1), acc[nt], 0, 0, 0);
  }

  // mask + in-register row softmax (row spread over 16 lanes; 4 rows per lane as j)
  #pragma unroll
  for (int j = 0; j < 4; ++j) {
    float mx = -3e38f;
    #pragma unroll
    for (int nt = 0; nt < 14; ++nt) {
      int t = nt*16 + r;
      float v = (t < len) ? acc[nt][j] : -1e9f;
      acc[nt][j] = v;
      mx = fmaxf(mx, v);
    }
    mx = fmaxf(mx, __shfl_xor(mx, 1));
    mx = fmaxf(mx, __shfl_xor(mx, 2));
    mx = fmaxf(mx, __shfl_xor(mx, 4));
    mx = fmaxf(mx, __shfl_xor(mx, 8));
    float sum = 0.f;
    #pragma unroll
    for (int nt = 0; nt < 14; ++nt) {
      float p = exp2f((acc[nt][j] - mx) * LOG2E);
      acc[nt][j] = p;
      sum += p;
    }
    sum += __shfl_xor(sum, 1);
    sum += __shfl_xor(sum, 2);
    sum += __shfl_xor(sum, 4);
    sum += __shfl_xor(sum, 8);
    float inv = 1.f / sum;
    #pragma unroll
    for (int nt = 0; nt < 14; ++nt) {
      union { __hip_bfloat16 hh; short s; } c;
      c.hh = __float2bfloat16(acc[nt][j] * inv);
      PT[wave][g*4 + j][nt*16 + r] = c.s;
    }
  }
  __syncthreads();   // all waves reach (mt clamped); orders PT writes before reads

  // PV: O_tile(16x48) = P(16x224) @ V(224x48)  [cols 40..47 are zero pad]
  f32x4 oacc0 = {0.f,0.f,0.f,0.f}, oacc1 = {0.f,0.f,0.f,0.f}, oacc2 = {0.f,0.f,0.f,0.f};
  #pragma unroll
  for (int ks = 0; ks < 7; ++ks) {
    bf16x8 pa = *(const bf16x8*)&PT[wave][r][ks*32 + g*8];
    bf16x8 v0 = *(const bf16x8*)&VT[r][ks*32 + g*8];
    bf16x8 v1 = *(const bf16x8*)&VT[16 + r][ks*32 + g*8];
    bf16x8 v2 = *(const bf16x8*)&VT[32 + r][ks*32 + g*8];
    oacc0 = __builtin_amdgcn_mfma_f32_16x16x32_bf16(pa, v0, oacc0, 0, 0, 0);
    oacc1 = __builtin_amdgcn_mfma_f32_16x16x32_bf16(pa, v1, oacc1, 0, 0, 0);
    oacc2 = __builtin_amdgcn_mfma_f32_16x16x32_bf16(pa, v2, oacc2, 0, 0, 0);
  }
  #pragma unroll
  for (int j = 0; j < 4; ++j) {
    int row = m0 + g*4 + j;
    if (row >= S_LEN) continue;
    float* op = O + ((size_t)row*CB + bl)*DT + h*DH;
    int d0 = r, d1 = 16 + r, d2 = 32 + r;
    op[d0] = oacc0[j];
    op[d1] = oacc1[j];
    if (d2 < DH) op[d2] = oacc2[j];
  }
}

// ---------------- layernorm ----------------
__global__ __launch_bounds__(256) void zz_ln(const float* __restrict__ X,
    const float* __restrict__ g, const float* __restrict__ bt, float* __restrict__ Y, int ntok)
{
  int tok = blockIdx.x*4 + (threadIdx.x >> 6);
  if (tok >= ntok) return;
  int lane = threadIdx.x & 63;
  const float* x = X + (size_t)tok*DT;
  float v0 = x[lane], v1 = x[lane + 64];
  float v2 = (lane < 32) ? x[lane + 128] : 0.f;
  float s = v0 + v1 + v2;
  for (int off = 32; off; off >>= 1) s += __shfl_xor(s, off);
  float mean = s * (1.f/160.f);
  float d0 = v0 - mean, d1 = v1 - mean, d2 = (lane < 32) ? (v2 - mean) : 0.f;
  float q = d0*d0 + d1*d1 + d2*d2;
  for (int off = 32; off; off >>= 1) q += __shfl_xor(q, off);
  float inv = 1.f / sqrtf(q * (1.f/160.f) + 1e-5f);
  float* y = Y + (size_t)tok*DT;
  y[lane]      = d0*inv*g[lane]      + bt[lane];
  y[lane + 64] = d1*inv*g[lane + 64] + bt[lane + 64];
  if (lane < 32) y[lane + 128] = d2*inv*g[lane + 128] + bt[lane + 128];
}

// ---------------- masked mean + feat concat ----------------
__global__ __launch_bounds__(256) void zz_agg(const float* __restrict__ XCH,
    const int* __restrict__ lengths, const float* __restrict__ emb, float* __restrict__ feat,
    int b0, int CB)
{
  int bl = blockIdx.x, tid = threadIdx.x;
  int b = b0 + bl;
  int len = lengths[b];
  if (tid < DT) {
    float acc = 0.f;
    for (int s = 0; s < len; ++s) acc += XCH[((size_t)s*CB + bl)*DT + tid];
    feat[(size_t)b*DFIN + tid] = acc / (float)(len + 1);
  } else if (tid < DFIN) {
    feat[(size_t)b*DFIN + tid] = emb[b*DI + (tid - DT)];
  }
}

// ======================================================================
extern "C" void kernel_launch(void* const* d_in, const int* in_sizes, int n_in,
                              void* d_out, int out_size, void* d_ws, size_t ws_size,
                              hipStream_t stream)
{
  (void)in_sizes; (void)n_in; (void)out_size;
  const float* src     = (const float*)d_in[0];
  const float* statc   = (const float*)d_in[1];
  const float* times   = (const float*)d_in[2];
  const int*   lengths = (const int*)  d_in[3];
  const float* R_u     = (const float*)d_in[4];
  const float* emb_w   = (const float*)d_in[5];
  const float* emb_b   = (const float*)d_in[6];
  const float* W1      = (const float*)d_in[7];
  const float* a1_s    = (const float*)d_in[8];
  const float* a1_d    = (const float*)d_in[9];
  const float* W2      = (const float*)d_in[10];
  const float* a2_s    = (const float*)d_in[11];
  const float* a2_d    = (const float*)d_in[12];
  const float* attn_in_w  = (const float*)d_in[13];
  const float* attn_in_b  = (const float*)d_in[14];
  const float* attn_out_w = (const float*)d_in[15];
  const float* attn_out_b = (const float*)d_in[16];
  const float* ff1_w = (const float*)d_in[17];
  const float* ff1_b = (const float*)d_in[18];
  const float* ff2_w = (const float*)d_in[19];
  const float* ff2_b = (const float*)d_in[20];
  const float* ln1_g = (const float*)d_in[21];
  const float* ln1_b = (const float*)d_in[22];
  const float* ln2_g = (const float*)d_in[23];
  const float* ln2_b = (const float*)d_in[24];
  const float* mlp1_w = (const float*)d_in[25];
  const float* mlp1_b = (const float*)d_in[26];
  const float* mlp2_w = (const float*)d_in[27];
  const float* mlp2_b = (const float*)d_in[28];

  // ---- small persistent buffers (floats) ----
  float* ws = (float*)d_ws;
  float* A1    = ws;                 // 663,552
  float* A2    = ws + 663552;        // 663,552
  float* SS    = ws + 1327104;       // 18,432
  float* SD    = ws + 1345536;       // 18,432
  float* SQB   = ws + 1363968;       // 512
  float* DSUM  = ws + 1364480;       // 64
  float* EMB   = ws + 1364544;       // 18,432
  float* FEAT  = ws + 1382976;       // 100,352
  float* FFEAT = ws + 1483328;       // 100,352
  // bf16 weight area (shorts), 16B-aligned
  short* wb = (short*)(ws + 1583680);
  short* W1T   = wb;                 // 746,496
  short* W2T   = wb + 746496;        // 746,496
  short* WTqkv = wb + 1492992;       // 153,600
  short* WTao  = wb + 1646592;       // 51,200
  short* WTf1  = wb + 1697792;       // 40,960
  short* WTf2  = wb + 1738752;       // 40,960
  const size_t CHBASE = 1583680 + 889856;   // = 2,473,536 floats
  float* CH = ws + CHBASE;

  // ---- pick largest chunk size that fits ws_size ----
  int CB = 8;
  const int cands[7] = {512, 256, 128, 64, 32, 16, 8};
  for (int c = 0; c < 7; ++c) {
    size_t need = 4ull * (CHBASE + 233920ull * (size_t)cands[c]);
    if (need <= ws_size) { CB = cands[c]; break; }
  }
  const int NCH = NB / CB;
  const int NTOKC = S_LEN * CB;

  float* XCH = CH;                         // 34,400*CB
  float* R0  = CH + (size_t)34400*CB;
  float* Xc  = R0;                         // 31,104*CB
  float* XPc = R0 + (size_t)31104*CB;      // 31,104*CB
  float* H1c = R0 + (size_t)62208*CB;      // 31,104*CB
  float* QKVc = R0;                        // 103,200*CB
  float* OAc  = R0 + (size_t)103200*CB;    // 34,400*CB
  float* Tc   = R0 + (size_t)137600*CB;    // 34,400*CB
  float* Yc   = R0 + (size_t)172000*CB;    // 27,520*CB

  hipMemsetAsync(DSUM, 0, 4, stream);
  zz_emb<<<dim3(CDIV(NB*DI,256)), 256, 0, stream>>>(statc, emb_w, emb_b, EMB);

  // ---- one-time weight transpose+bf16 conversions ----
  zz_wcvt<<<dim3(CDIV(FINP*FINP,256)), 256, 0, stream>>>(W1, W1T, FIN, FIN, FINP, FINP);
  zz_wcvt<<<dim3(CDIV(FINP*FINP,256)), 256, 0, stream>>>(W2, W2T, FIN, FIN, FINP, FINP);
  for (int l = 0; l < 2; ++l) {
    zz_wcvt<<<dim3(CDIV(480*160,256)), 256, 0, stream>>>(attn_in_w + (size_t)l*DT*3*DT,
        WTqkv + (size_t)l*76800, DT, 3*DT, DT, 3*DT);
    zz_wcvt<<<dim3(CDIV(160*160,256)), 256, 0, stream>>>(attn_out_w + (size_t)l*DT*DT,
        WTao + (size_t)l*25600, DT, DT, DT, DT);
    zz_wcvt<<<dim3(CDIV(128*160,256)), 256, 0, stream>>>(ff1_w + (size_t)l*DT*NHID,
        WTf1 + (size_t)l*20480, DT, NHID, DT, NHID);
    zz_wcvt<<<dim3(CDIV(160*128,256)), 256, 0, stream>>>(ff2_w + (size_t)l*NHID*DT,
        WTf2 + (size_t)l*20480, NHID, DT, NHID, DT);
  }

  for (int ch = 0; ch < NCH; ++ch) {
    int b0 = ch * CB;
    // ---- GAT stack (chunk) ----
    zz_build_x<<<dim3(CDIV(CB*DI*S_LEN,256)), 256, 0, stream>>>(src, R_u, Xc, b0, CB);
    zz_zeropad<<<dim3(CDIV(CB*DI,256)), 256, 0, stream>>>(Xc, CB);
    zz_gat_mfma<<<dim3(2, CB), 256, 0, stream>>>(Xc, W1T, XPc, CB);
    zz_gat_attvec<<<dim3(DI, CB), 64, 0, stream>>>(XPc, a1_s, a1_d, SS, SD, b0);
    zz_gat_alpha<<<dim3(CB), 256, 0, stream>>>(SS, SD, (const float*)nullptr, A1, b0);
    zz_gat_apply<<<dim3(4, CB), 256, 0, stream>>>(A1, XPc, H1c, 0, b0, CB);
    zz_zeropad<<<dim3(CDIV(CB*DI,256)), 256, 0, stream>>>(H1c, CB);
    zz_gat_mfma<<<dim3(2, CB), 256, 0, stream>>>(H1c, W2T, XPc, CB);
    zz_gat_attvec<<<dim3(DI, CB), 64, 0, stream>>>(XPc, a2_s, a2_d, SS, SD, b0);
    zz_gat_alpha<<<dim3(CB), 256, 0, stream>>>(SS, SD, A1, A2, b0);
    zz_gat_apply<<<dim3(4, CB), 256, 0, stream>>>(A2, XPc, XCH, 1, b0, CB);
    zz_pe<<<dim3(CDIV(CB*S_LEN*16,256)), 256, 0, stream>>>(times, XCH, b0, CB);

    // ---- transformer (chunk) ----
    for (int l = 0; l < 2; ++l) {
      zz_mgemm<0,0><<<dim3(CDIV(NTOKC,64)), 256, 0, stream>>>(XCH,
          WTqkv + (size_t)l*76800, attn_in_b + l*3*DT, nullptr, QKVc, NTOKC, 3*DT, DT);
      zz_fattn<<<dim3(CB*NH, 4), 256, 0, stream>>>(QKVc, lengths, OAc, b0, CB);
      zz_mgemm<0,1><<<dim3(CDIV(NTOKC,64)), 256, 0, stream>>>(OAc,
          WTao + (size_t)l*25600, attn_out_b + l*DT, XCH, Tc, NTOKC, DT, DT);
      zz_ln<<<dim3(CDIV(NTOKC,4)), 256, 0, stream>>>(Tc, ln1_g + l*DT, ln1_b + l*DT, XCH, NTOKC);
      zz_mgemm<1,0><<<dim3(CDIV(NTOKC,64)), 256, 0, stream>>>(XCH,
          WTf1 + (size_t)l*20480, ff1_b + l*NHID, nullptr, Yc, NTOKC, NHID, DT);
      zz_mgemm<0,1><<<dim3(CDIV(NTOKC,64)), 256, 0, stream>>>(Yc,
          WTf2 + (size_t)l*20480, ff2_b + l*DT, XCH, Tc, NTOKC, DT, NHID);
      zz_ln<<<dim3(CDIV(NTOKC,4)), 256, 0, stream>>>(Tc, ln2_g + l*DT, ln2_b + l*DT, XCH, NTOKC);
    }

    zz_agg<<<dim3(CB), 256, 0, stream>>>(XCH, lengths, EMB, FEAT, b0, CB);
  }

  // ---- distance from alpha2 (full batch) ----
  zz_sq<<<dim3(NB), 64, 0, stream>>>(A2, SQB);
  zz_dist<<<dim3(8, 8), 256, 0, stream>>>(A2, SQB, DSUM);
  zz_dist_fin<<<1, 1, 0, stream>>>(DSUM, (float*)d_out + 1024);

  // ---- head (f32, tiny) ----
  zz_gemm<1,0><<<dim3(CDIV(DFIN,128), CDIV(NB,64)), 256, 0, stream>>>(FEAT, mlp1_w, mlp1_b,
      nullptr, FFEAT, NB, DFIN, DFIN);
  zz_gemm<0,0><<<dim3(1, CDIV(NB,64)), 256, 0, stream>>>(FFEAT, mlp2_w, mlp2_b,
      nullptr, (float*)d_out, NB, 2, DFIN);
}

// Round 8
// 3031.638 us; speedup vs baseline: 1.3150x; 1.3150x over previous
//
#include <hip/hip_runtime.h>
#include <hip/hip_bf16.h>
#include <math.h>

#define S_LEN 215
#define NB    512
#define DI    36
#define DMODEL 144
#define DT    160
#define NH    4
#define DH    40
#define NHID  128
#define FIN   860
#define FINP  864          // K-padded
#define DFIN  196
#define TP    226          // LDS t-stride (shorts): 113 dwords per row (odd -> conflict-free)
#define CDIV(a,b) (((a)+(b)-1)/(b))

typedef __attribute__((ext_vector_type(8))) short bf16x8;
typedef __attribute__((ext_vector_type(4))) float f32x4;

__device__ inline bf16x8 zz_cvt8(const float* __restrict__ p) {
  float4 lo = *(const float4*)p;
  float4 hi = *(const float4*)(p + 4);
  union { bf16x8 v; __hip_bfloat16 h[8]; } u;
  u.h[0] = __float2bfloat16(lo.x); u.h[1] = __float2bfloat16(lo.y);
  u.h[2] = __float2bfloat16(lo.z); u.h[3] = __float2bfloat16(lo.w);
  u.h[4] = __float2bfloat16(hi.x); u.h[5] = __float2bfloat16(hi.y);
  u.h[6] = __float2bfloat16(hi.z); u.h[7] = __float2bfloat16(hi.w);
  return u.v;
}

__device__ inline bf16x8 zz_cvt8a(const float t[8]) {
  union { bf16x8 v; __hip_bfloat16 h[8]; } u;
  #pragma unroll
  for (int i = 0; i < 8; ++i) u.h[i] = __float2bfloat16(t[i]);
  return u.v;
}

// ---------------- weight transpose + bf16 convert: WT[n][k] = bf16(W[k][n]) ----------------
__global__ __launch_bounds__(256) void zz_wcvt(const float* __restrict__ W,
    short* __restrict__ WT, int K, int N, int Kpad, int Npad)
{
  int idx = blockIdx.x*256 + threadIdx.x;
  if (idx >= Npad*Kpad) return;
  int n = idx / Kpad, k = idx % Kpad;
  float v = (n < N && k < K) ? W[(size_t)k*N + n] : 0.f;
  union { __hip_bfloat16 h; short s; } c;
  c.h = __float2bfloat16(v);
  WT[idx] = c.s;
}

// ---------------- build x chunk ----------------
__global__ __launch_bounds__(256) void zz_build_x(const float* __restrict__ src,
    const float* __restrict__ R_u, float* __restrict__ X, int b0, int CB)
{
  int idx = blockIdx.x*256 + threadIdx.x;           // (bl,i,s)
  if (idx >= CB*DI*S_LEN) return;
  int s = idx % S_LEN; int t = idx / S_LEN; int i = t % DI; int bl = t / DI;
  float v = src[((size_t)s*NB + b0 + bl)*(2*DI) + i];
  float4 r = *(const float4*)(R_u + i*4);
  float4 o;
  o.x = fmaxf(v*r.x, 0.f); o.y = fmaxf(v*r.y, 0.f);
  o.z = fmaxf(v*r.z, 0.f); o.w = fmaxf(v*r.w, 0.f);
  *(float4*)(X + (size_t)(bl*DI + i)*FINP + s*4) = o;
}

// ---------------- zero pad cols 860..863 ----------------
__global__ __launch_bounds__(256) void zz_zeropad(float* __restrict__ buf, int CB)
{
  int idx = blockIdx.x*256 + threadIdx.x;
  if (idx >= CB*DI) return;
  float4 z = {0.f,0.f,0.f,0.f};
  *(float4*)(buf + (size_t)idx*FINP + FIN) = z;
}

// ---------------- positional encoding ----------------
__global__ __launch_bounds__(256) void zz_pe(const float* __restrict__ times,
    float* __restrict__ XCH, int b0, int CB)
{
  int idx = blockIdx.x*256 + threadIdx.x;           // (tl, k)
  if (idx >= CB*S_LEN*16) return;
  int k = idx & 15; int tl = idx >> 4;
  int bl = tl % CB; int s = tl / CB;
  int j = k & 7;
  float ts = powf(215.f, (float)j * (1.f/7.f)) * 100.f;
  float sc = times[(size_t)s*NB + b0 + bl] / ts;
  XCH[(size_t)tl*DT + DMODEL + k] = (k < 8) ? sinf(sc) : cosf(sc);
}

// ---------------- emb ----------------
__global__ __launch_bounds__(256) void zz_emb(const float* __restrict__ st,
    const float* __restrict__ w, const float* __restrict__ bias, float* __restrict__ emb)
{
  int idx = blockIdx.x*256 + threadIdx.x;
  if (idx >= NB*DI) return;
  int b = idx / DI, k = idx % DI;
  float acc = bias[k];
  #pragma unroll
  for (int j = 0; j < 9; ++j) acc = fmaf(st[b*9 + j], w[j*DI + k], acc);
  emb[idx] = acc;
}

// ---------------- GAT GEMM via MFMA ----------------
__global__ __launch_bounds__(256) void zz_gat_mfma(const float* __restrict__ X,
    const short* __restrict__ WT, float* __restrict__ XP, int CB)
{
  int bl = blockIdx.y, half = blockIdx.x;
  int wave = threadIdx.x >> 6, lane = threadIdx.x & 63;
  int r = lane & 15, g = lane >> 4;
  const float* Xb = X + (size_t)bl*DI*FINP;
  float* XPb = XP + (size_t)bl*DI*FINP;
  int p0 = half ? 14 : 0, p1 = half ? 27 : 14;
  int ntasks = 3 * (p1 - p0);
  for (int task = wave; task < ntasks; task += 4) {
    int mt = task % 3; int ntp = p0 + task / 3;
    int m0 = mt*16;
    int arow = m0 + r; if (arow > DI-1) arow = DI-1;
    const float* Ap = Xb + (size_t)arow*FINP + g*8;
    int n0 = ntp*32;
    const short* B0 = WT + (size_t)(n0 + r)*FINP + g*8;
    const short* B1 = B0 + (size_t)16*FINP;
    f32x4 acc0 = {0.f,0.f,0.f,0.f}, acc1 = {0.f,0.f,0.f,0.f};
    #pragma unroll 3
    for (int k0 = 0; k0 < FINP; k0 += 32) {
      bf16x8 af = zz_cvt8(Ap + k0);
      bf16x8 b0 = *(const bf16x8*)(B0 + k0);
      bf16x8 b1 = *(const bf16x8*)(B1 + k0);
      acc0 = __builtin_amdgcn_mfma_f32_16x16x32_bf16(af, b0, acc0, 0, 0, 0);
      acc1 = __builtin_amdgcn_mfma_f32_16x16x32_bf16(af, b1, acc1, 0, 0, 0);
    }
    #pragma unroll
    for (int j = 0; j < 4; ++j) {
      int row = m0 + g*4 + j;
      if (row < DI) {
        int c0 = n0 + r, c1 = n0 + 16 + r;
        if (c0 < FIN) XPb[(size_t)row*FINP + c0] = acc0[j];
        if (c1 < FIN) XPb[(size_t)row*FINP + c1] = acc1[j];
      }
    }
  }
}

// ---------------- per-row dots ----------------
__global__ __launch_bounds__(64) void zz_gat_attvec(const float* __restrict__ XP,
    const float* __restrict__ a_s, const float* __restrict__ a_d,
    float* __restrict__ ss, float* __restrict__ sd, int b0)
{
  int i = blockIdx.x, bl = blockIdx.y, lane = threadIdx.x;
  const float* row = XP + ((size_t)bl*DI + i)*FINP;
  float ps = 0.f, pd = 0.f;
  for (int k = lane; k < FIN; k += 64) {
    float v = row[k];
    ps = fmaf(v, a_s[k], ps);
    pd = fmaf(v, a_d[k], pd);
  }
  for (int off = 32; off; off >>= 1) { ps += __shfl_xor(ps, off); pd += __shfl_xor(pd, off); }
  if (!lane) { ss[(b0 + bl)*DI + i] = ps; sd[(b0 + bl)*DI + i] = pd; }
}

// ---------------- alpha softmax ----------------
__global__ __launch_bounds__(256) void zz_gat_alpha(const float* __restrict__ ss,
    const float* __restrict__ sd, const float* __restrict__ edge, float* __restrict__ alpha, int b0)
{
  int b = b0 + blockIdx.x;
  int wv = threadIdx.x >> 6, lane = threadIdx.x & 63;
  for (int i = wv; i < DI; i += 4) {
    float di = sd[b*DI + i];
    float e = -3e38f, x = 0.f;
    if (lane < DI) {
      x = di + ss[b*DI + lane];
      x = (x >= 0.f) ? x : 0.2f*x;
      e = x;
    }
    float m = e;
    for (int off = 32; off; off >>= 1) m = fmaxf(m, __shfl_xor(m, off));
    float p = (lane < DI) ? expf(e - m) : 0.f;
    float s = p;
    for (int off = 32; off; off >>= 1) s += __shfl_xor(s, off);
    if (lane < DI) {
      float a = p / s;
      size_t o = ((size_t)b*DI + i)*DI + lane;
      if (edge) a *= edge[o];
      alpha[o] = a;
    }
  }
}

// ---------------- gat apply ----------------
__global__ __launch_bounds__(256) void zz_gat_apply(const float* __restrict__ alpha,
    const float* __restrict__ XP, float* __restrict__ out, int mode, int b0, int CB)
{
  __shared__ float Al[DI][37];
  __shared__ float Xs[DI][260];
  int bl = blockIdx.y, n0 = blockIdx.x * 256;
  int tid = threadIdx.x;
  int nt = tid & 63, mg = tid >> 6;
  const float* ab = alpha + ((size_t)(b0 + bl))*DI*DI;
  for (int i = tid; i < DI*DI; i += 256) Al[i/DI][i%DI] = ab[i];
  const float* XPb = XP + (size_t)bl*DI*FINP;
  for (int i = tid; i < DI*256; i += 256) {
    int k = i >> 8, nn = i & 255, gn = n0 + nn;
    Xs[k][nn] = (gn < FIN) ? XPb[(size_t)k*FINP + gn] : 0.f;
  }
  __syncthreads();
  float acc[9][4] = {};
  #pragma unroll 4
  for (int k = 0; k < DI; ++k) {
    float4 x4 = *(const float4*)&Xs[k][nt*4];
    float xb[4] = {x4.x, x4.y, x4.z, x4.w};
    #pragma unroll
    for (int m = 0; m < 9; ++m) {
      float av = Al[mg*9 + m][k];
      #pragma unroll
      for (int v = 0; v < 4; ++v) acc[m][v] = fmaf(av, xb[v], acc[m][v]);
    }
  }
  int gn = n0 + nt*4;
  if (gn < FIN) {
    if (mode == 0) {
      float* ob = out + (size_t)bl*DI*FINP;
      #pragma unroll
      for (int m = 0; m < 9; ++m) {
        float4 o4 = {acc[m][0], acc[m][1], acc[m][2], acc[m][3]};
        *(float4*)(ob + (size_t)(mg*9 + m)*FINP + gn) = o4;
      }
    } else {
      int s = gn >> 2;
      float* op = out + ((size_t)s*CB + bl)*DT;
      #pragma unroll
      for (int m = 0; m < 9; ++m) {
        float4 o4 = {acc[m][0], acc[m][1], acc[m][2], acc[m][3]};
        *(float4*)(op + (mg*9 + m)*4) = o4;
      }
    }
  }
}

// ---------------- distance helpers ----------------
__global__ __launch_bounds__(64) void zz_sq(const float* __restrict__ A, float* __restrict__ sq)
{
  int i = blockIdx.x, lane = threadIdx.x;
  const float* row = A + (size_t)i*(DI*DI);
  float s = 0.f;
  for (int k = lane; k < DI*DI; k += 64) { float v = row[k]; s = fmaf(v, v, s); }
  for (int off = 32; off; off >>= 1) s += __shfl_xor(s, off);
  if (!lane) sq[i] = s;
}

__global__ __launch_bounds__(256) void zz_dist(const float* __restrict__ A,
    const float* __restrict__ sq, float* __restrict__ dsum)
{
  __shared__ float Ai[64][65], Aj[64][65];
  __shared__ float red[256];
  int i0 = blockIdx.y*64, j0 = blockIdx.x*64;
  int tid = threadIdx.x, tx = tid % 16, ty = tid / 16;
  float acc[4][4] = {};
  for (int k0 = 0; k0 < DI*DI; k0 += 64) {
    for (int t = tid; t < 64*64; t += 256) {
      int r = t >> 6, kk = t & 63, gk = k0 + kk;
      float vi = 0.f, vj = 0.f;
      if (gk < DI*DI) {
        vi = A[(size_t)(i0 + r)*(DI*DI) + gk];
        vj = A[(size_t)(j0 + r)*(DI*DI) + gk];
      }
      Ai[r][kk] = vi; Aj[r][kk] = vj;
    }
    __syncthreads();
    #pragma unroll 8
    for (int kk = 0; kk < 64; ++kk) {
      float a[4], bb[4];
      #pragma unroll
      for (int u = 0; u < 4; ++u) a[u]  = Ai[ty*4 + u][kk];
      #pragma unroll
      for (int u = 0; u < 4; ++u) bb[u] = Aj[tx*4 + u][kk];
      #pragma unroll
      for (int u = 0; u < 4; ++u)
        #pragma unroll
        for (int v = 0; v < 4; ++v) acc[u][v] = fmaf(a[u], bb[v], acc[u][v]);
    }
    __syncthreads();
  }
  float s = 0.f;
  #pragma unroll
  for (int u = 0; u < 4; ++u)
    #pragma unroll
    for (int v = 0; v < 4; ++v) {
      float d2 = sq[i0 + ty*4 + u] + sq[j0 + tx*4 + v] - 2.f*acc[u][v];
      d2 = fmaxf(d2, 0.f);
      s += sqrtf(d2 + 1e-12f);
    }
  red[tid] = s; __syncthreads();
  for (int st = 128; st; st >>= 1) { if (tid < st) red[tid] += red[tid + st]; __syncthreads(); }
  if (!tid) atomicAdd(dsum, red[0]);
}

__global__ void zz_dist_fin(const float* dsum, float* out)
{
  out[0] = dsum[0] * (1.f/((float)NB*(float)NB));
}

// ---------------- token GEMM via MFMA ----------------
template<int RELU, int RES>
__global__ __launch_bounds__(256) void zz_mgemm(const float* __restrict__ A,
    const short* __restrict__ BT, const float* __restrict__ bias,
    const float* __restrict__ res, float* __restrict__ C, int M, int N, int K)
{
  int wave = threadIdx.x >> 6, lane = threadIdx.x & 63;
  int m0 = blockIdx.x*64 + wave*16;
  if (m0 >= M) return;
  int r = lane & 15, g = lane >> 4;
  int arow = m0 + r; if (arow >= M) arow = M - 1;
  const float* Ap = A + (size_t)arow*K + g*8;
  int NP = N >> 5;
  for (int ntp = 0; ntp < NP; ++ntp) {
    int n0 = ntp*32;
    const short* B0 = BT + (size_t)(n0 + r)*K + g*8;
    const short* B1 = B0 + (size_t)16*K;
    f32x4 acc0 = {0.f,0.f,0.f,0.f}, acc1 = {0.f,0.f,0.f,0.f};
    #pragma unroll 5
    for (int k0 = 0; k0 < K; k0 += 32) {
      bf16x8 af = zz_cvt8(Ap + k0);
      bf16x8 b0 = *(const bf16x8*)(B0 + k0);
      bf16x8 b1 = *(const bf16x8*)(B1 + k0);
      acc0 = __builtin_amdgcn_mfma_f32_16x16x32_bf16(af, b0, acc0, 0, 0, 0);
      acc1 = __builtin_amdgcn_mfma_f32_16x16x32_bf16(af, b1, acc1, 0, 0, 0);
    }
    #pragma unroll
    for (int j = 0; j < 4; ++j) {
      int row = m0 + g*4 + j;
      if (row >= M) continue;
      int c0 = n0 + r, c1 = n0 + 16 + r;
      float v0 = acc0[j] + bias[c0];
      float v1 = acc1[j] + bias[c1];
      if (RES) { v0 += res[(size_t)row*N + c0]; v1 += res[(size_t)row*N + c1]; }
      if (RELU) { v0 = fmaxf(v0, 0.f); v1 = fmaxf(v1, 0.f); }
      C[(size_t)row*N + c0] = v0;
      C[(size_t)row*N + c1] = v1;
    }
  }
}

// ---------------- f32 tiled GEMM (head) ----------------
template<int RELU, int RES>
__global__ __launch_bounds__(256) void zz_gemm(const float* __restrict__ A,
    const float* __restrict__ Bw, const float* __restrict__ bias,
    const float* __restrict__ res, float* __restrict__ C, int M, int N, int K)
{
  __shared__ float As[64][33];
  __shared__ float Bs[32][136];
  int m0 = blockIdx.y*64, n0 = blockIdx.x*128;
  int tid = threadIdx.x, tx = tid & 15, ty = tid >> 4;
  float acc[4][8] = {};
  for (int k0 = 0; k0 < K; k0 += 32) {
    for (int i = tid; i < 64*32; i += 256) {
      int rr = i >> 5, kk = i & 31;
      int gm = m0 + rr, gk = k0 + kk;
      As[rr][kk] = (gm < M && gk < K) ? A[(size_t)gm*K + gk] : 0.f;
    }
    for (int i = tid; i < 32*128; i += 256) {
      int kk = i >> 7, n = i & 127;
      int gk = k0 + kk, gn = n0 + n;
      Bs[kk][n] = (gk < K && gn < N) ? Bw[(size_t)gk*N + gn] : 0.f;
    }
    __syncthreads();
    #pragma unroll 4
    for (int kk = 0; kk < 32; ++kk) {
      float a[4];
      #pragma unroll
      for (int u = 0; u < 4; ++u) a[u] = As[ty*4 + u][kk];
      float4 b0 = *(const float4*)&Bs[kk][tx*8];
      float4 b1 = *(const float4*)&Bs[kk][tx*8 + 4];
      float b[8] = {b0.x,b0.y,b0.z,b0.w,b1.x,b1.y,b1.z,b1.w};
      #pragma unroll
      for (int u = 0; u < 4; ++u)
        #pragma unroll
        for (int v = 0; v < 8; ++v) acc[u][v] = fmaf(a[u], b[v], acc[u][v]);
    }
    __syncthreads();
  }
  #pragma unroll
  for (int u = 0; u < 4; ++u) {
    int gm = m0 + ty*4 + u;
    if (gm >= M) continue;
    #pragma unroll
    for (int v = 0; v < 8; ++v) {
      int gn = n0 + tx*8 + v;
      if (gn >= N) continue;
      float val = acc[u][v] + bias[gn];
      if (RES) val += res[(size_t)gm*N + gn];
      if (RELU) val = fmaxf(val, 0.f);
      C[(size_t)gm*N + gn] = val;
    }
  }
}

// ---------------- fused MFMA attention v2: one block per (bl,h); K,V staged once ----------------
// LDS: K_lds[224][66] bf16 (d 0..63, zeros d>=40), VT[48][226] bf16, PT[4][16][226] bf16.
// All row strides odd in dwords -> conflict-free fragment reads.
__global__ __launch_bounds__(256) void zz_fattn(const float* __restrict__ QKV,
    const int* __restrict__ lengths, float* __restrict__ O, int b0, int CB)
{
  __shared__ short K_lds[224][66];
  __shared__ short VT[48][TP];
  __shared__ short PT[4][16][TP];
  const float LOG2E = 1.44269504088896f;
  int bh = blockIdx.x, bl = bh >> 2, h = bh & 3;
  int tid = threadIdx.x, wave = tid >> 6, lane = tid & 63;
  int len = lengths[b0 + bl];

  // stage K (row-major, padded) and V^T, bf16, coalesced global reads
  for (int i = tid; i < 224*64; i += 256) {
    int t = i >> 6, d = i & 63;
    float kv = 0.f, vv = 0.f;
    if (t < S_LEN && d < DH) {
      const float* base = QKV + ((size_t)t*CB + bl)*(3*DT) + DT + h*DH + d;
      kv = base[0];        // K
      vv = base[DT];       // V
    }
    union { __hip_bfloat16 hh; short s; } ck, cv;
    ck.hh = __float2bfloat16(kv);
    K_lds[t][d] = ck.s;
    if (d < 48) { cv.hh = __float2bfloat16(vv); VT[d][t] = cv.s; }
  }
  __syncthreads();

  int r = lane & 15, g = lane >> 4;
  for (int mt = wave; mt < 14; mt += 4) {
    int m0 = mt*16;
    // Q A-frags (k 0..31 and 32..63), scale folded in
    int qrow = m0 + r; if (qrow > S_LEN-1) qrow = S_LEN-1;
    const float* qp = QKV + ((size_t)qrow*CB + bl)*(3*DT) + h*DH;
    bf16x8 qf0, qf1;
    {
      float t0[8], t1[8];
      #pragma unroll
      for (int u = 0; u < 8; ++u) t0[u] = qp[g*8 + u] * 0.15811388300841897f;
      #pragma unroll
      for (int u = 0; u < 8; ++u) t1[u] = (g == 0) ? qp[32 + u] * 0.15811388300841897f : 0.f;
      qf0 = zz_cvt8a(t0); qf1 = zz_cvt8a(t1);
    }
    // QK^T over 14 key tiles (B from LDS)
    f32x4 acc[14];
    #pragma unroll
    for (int nt = 0; nt < 14; ++nt) acc[nt] = (f32x4){0.f,0.f,0.f,0.f};
    #pragma unroll
    for (int nt = 0; nt < 14; ++nt) {
      int trow = nt*16 + r; if (trow > S_LEN-1) trow = S_LEN-1;
      bf16x8 b0 = *(const bf16x8*)&K_lds[trow][g*8];
      bf16x8 b1 = *(const bf16x8*)&K_lds[trow][32 + g*8];
      acc[nt] = __builtin_amdgcn_mfma_f32_16x16x32_bf16(qf0, b0, acc[nt], 0, 0, 0);
      acc[nt] = __builtin_amdgcn_mfma_f32_16x16x32_bf16(qf1, b1, acc[nt], 0, 0, 0);
    }
    // mask + in-register row softmax; normalized P -> PT[wave] (bf16)
    #pragma unroll
    for (int j = 0; j < 4; ++j) {
      float mx = -3e38f;
      #pragma unroll
      for (int nt = 0; nt < 14; ++nt) {
        int t = nt*16 + r;
        float v = (t < len) ? acc[nt][j] : -1e9f;
        acc[nt][j] = v;
        mx = fmaxf(mx, v);
      }
      mx = fmaxf(mx, __shfl_xor(mx, 1));
      mx = fmaxf(mx, __shfl_xor(mx, 2));
      mx = fmaxf(mx, __shfl_xor(mx, 4));
      mx = fmaxf(mx, __shfl_xor(mx, 8));
      float sum = 0.f;
      #pragma unroll
      for (int nt = 0; nt < 14; ++nt) {
        float p = exp2f((acc[nt][j] - mx) * LOG2E);
        acc[nt][j] = p;
        sum += p;
      }
      sum += __shfl_xor(sum, 1);
      sum += __shfl_xor(sum, 2);
      sum += __shfl_xor(sum, 4);
      sum += __shfl_xor(sum, 8);
      float inv = 1.f / sum;
      #pragma unroll
      for (int nt = 0; nt < 14; ++nt) {
        union { __hip_bfloat16 hh; short s; } c;
        c.hh = __float2bfloat16(acc[nt][j] * inv);
        PT[wave][g*4 + j][nt*16 + r] = c.s;
      }
    }
    // PV: O_tile(16x48) = P(16x224) @ V(224x48); PT is wave-private (no barrier)
    f32x4 oacc0 = {0.f,0.f,0.f,0.f}, oacc1 = {0.f,0.f,0.f,0.f}, oacc2 = {0.f,0.f,0.f,0.f};
    #pragma unroll
    for (int ks = 0; ks < 7; ++ks) {
      bf16x8 pa = *(const bf16x8*)&PT[wave][r][ks*32 + g*8];
      bf16x8 v0 = *(const bf16x8*)&VT[r][ks*32 + g*8];
      bf16x8 v1 = *(const bf16x8*)&VT[16 + r][ks*32 + g*8];
      bf16x8 v2 = *(const bf16x8*)&VT[32 + r][ks*32 + g*8];
      oacc0 = __builtin_amdgcn_mfma_f32_16x16x32_bf16(pa, v0, oacc0, 0, 0, 0);
      oacc1 = __builtin_amdgcn_mfma_f32_16x16x32_bf16(pa, v1, oacc1, 0, 0, 0);
      oacc2 = __builtin_amdgcn_mfma_f32_16x16x32_bf16(pa, v2, oacc2, 0, 0, 0);
    }
    #pragma unroll
    for (int j = 0; j < 4; ++j) {
      int row = m0 + g*4 + j;
      if (row >= S_LEN) continue;
      float* op = O + ((size_t)row*CB + bl)*DT + h*DH;
      op[r] = oacc0[j];
      op[16 + r] = oacc1[j];
      if (32 + r < DH) op[32 + r] = oacc2[j];
    }
  }
}

// ---------------- layernorm ----------------
__global__ __launch_bounds__(256) void zz_ln(const float* __restrict__ X,
    const float* __restrict__ g, const float* __restrict__ bt, float* __restrict__ Y, int ntok)
{
  int tok = blockIdx.x*4 + (threadIdx.x >> 6);
  if (tok >= ntok) return;
  int lane = threadIdx.x & 63;
  const float* x = X + (size_t)tok*DT;
  float v0 = x[lane], v1 = x[lane + 64];
  float v2 = (lane < 32) ? x[lane + 128] : 0.f;
  float s = v0 + v1 + v2;
  for (int off = 32; off; off >>= 1) s += __shfl_xor(s, off);
  float mean = s * (1.f/160.f);
  float d0 = v0 - mean, d1 = v1 - mean, d2 = (lane < 32) ? (v2 - mean) : 0.f;
  float q = d0*d0 + d1*d1 + d2*d2;
  for (int off = 32; off; off >>= 1) q += __shfl_xor(q, off);
  float inv = 1.f / sqrtf(q * (1.f/160.f) + 1e-5f);
  float* y = Y + (size_t)tok*DT;
  y[lane]      = d0*inv*g[lane]      + bt[lane];
  y[lane + 64] = d1*inv*g[lane + 64] + bt[lane + 64];
  if (lane < 32) y[lane + 128] = d2*inv*g[lane + 128] + bt[lane + 128];
}

// ---------------- masked mean + feat concat ----------------
__global__ __launch_bounds__(256) void zz_agg(const float* __restrict__ XCH,
    const int* __restrict__ lengths, const float* __restrict__ emb, float* __restrict__ feat,
    int b0, int CB)
{
  int bl = blockIdx.x, tid = threadIdx.x;
  int b = b0 + bl;
  int len = lengths[b];
  if (tid < DT) {
    float acc = 0.f;
    for (int s = 0; s < len; ++s) acc += XCH[((size_t)s*CB + bl)*DT + tid];
    feat[(size_t)b*DFIN + tid] = acc / (float)(len + 1);
  } else if (tid < DFIN) {
    feat[(size_t)b*DFIN + tid] = emb[b*DI + (tid - DT)];
  }
}

// ======================================================================
extern "C" void kernel_launch(void* const* d_in, const int* in_sizes, int n_in,
                              void* d_out, int out_size, void* d_ws, size_t ws_size,
                              hipStream_t stream)
{
  (void)in_sizes; (void)n_in; (void)out_size;
  const float* src     = (const float*)d_in[0];
  const float* statc   = (const float*)d_in[1];
  const float* times   = (const float*)d_in[2];
  const int*   lengths = (const int*)  d_in[3];
  const float* R_u     = (const float*)d_in[4];
  const float* emb_w   = (const float*)d_in[5];
  const float* emb_b   = (const float*)d_in[6];
  const float* W1      = (const float*)d_in[7];
  const float* a1_s    = (const float*)d_in[8];
  const float* a1_d    = (const float*)d_in[9];
  const float* W2      = (const float*)d_in[10];
  const float* a2_s    = (const float*)d_in[11];
  const float* a2_d    = (const float*)d_in[12];
  const float* attn_in_w  = (const float*)d_in[13];
  const float* attn_in_b  = (const float*)d_in[14];
  const float* attn_out_w = (const float*)d_in[15];
  const float* attn_out_b = (const float*)d_in[16];
  const float* ff1_w = (const float*)d_in[17];
  const float* ff1_b = (const float*)d_in[18];
  const float* ff2_w = (const float*)d_in[19];
  const float* ff2_b = (const float*)d_in[20];
  const float* ln1_g = (const float*)d_in[21];
  const float* ln1_b = (const float*)d_in[22];
  const float* ln2_g = (const float*)d_in[23];
  const float* ln2_b = (const float*)d_in[24];
  const float* mlp1_w = (const float*)d_in[25];
  const float* mlp1_b = (const float*)d_in[26];
  const float* mlp2_w = (const float*)d_in[27];
  const float* mlp2_b = (const float*)d_in[28];

  // ---- small persistent buffers (floats) ----
  float* ws = (float*)d_ws;
  float* A1    = ws;                 // 663,552
  float* A2    = ws + 663552;        // 663,552
  float* SS    = ws + 1327104;       // 18,432
  float* SD    = ws + 1345536;       // 18,432
  float* SQB   = ws + 1363968;       // 512
  float* DSUM  = ws + 1364480;       // 64
  float* EMB   = ws + 1364544;       // 18,432
  float* FEAT  = ws + 1382976;       // 100,352
  float* FFEAT = ws + 1483328;       // 100,352
  // bf16 weight area (shorts), 16B-aligned
  short* wb = (short*)(ws + 1583680);
  short* W1T   = wb;                 // 746,496
  short* W2T   = wb + 746496;        // 746,496
  short* WTqkv = wb + 1492992;       // 153,600
  short* WTao  = wb + 1646592;       // 51,200
  short* WTf1  = wb + 1697792;       // 40,960
  short* WTf2  = wb + 1738752;       // 40,960
  const size_t CHBASE = 1583680 + 889856;   // = 2,473,536 floats
  float* CH = ws + CHBASE;

  // ---- pick largest chunk size that fits ws_size ----
  int CB = 8;
  const int cands[7] = {512, 256, 128, 64, 32, 16, 8};
  for (int c = 0; c < 7; ++c) {
    size_t need = 4ull * (CHBASE + 233920ull * (size_t)cands[c]);
    if (need <= ws_size) { CB = cands[c]; break; }
  }
  const int NCH = NB / CB;
  const int NTOKC = S_LEN * CB;

  float* XCH = CH;                         // 34,400*CB
  float* R0  = CH + (size_t)34400*CB;
  float* Xc  = R0;                         // 31,104*CB
  float* XPc = R0 + (size_t)31104*CB;      // 31,104*CB
  float* H1c = R0 + (size_t)62208*CB;      // 31,104*CB
  float* QKVc = R0;                        // 103,200*CB
  float* OAc  = R0 + (size_t)103200*CB;    // 34,400*CB
  float* Tc   = R0 + (size_t)137600*CB;    // 34,400*CB
  float* Yc   = R0 + (size_t)172000*CB;    // 27,520*CB

  hipMemsetAsync(DSUM, 0, 4, stream);
  zz_emb<<<dim3(CDIV(NB*DI,256)), 256, 0, stream>>>(statc, emb_w, emb_b, EMB);

  // ---- one-time weight transpose+bf16 conversions ----
  zz_wcvt<<<dim3(CDIV(FINP*FINP,256)), 256, 0, stream>>>(W1, W1T, FIN, FIN, FINP, FINP);
  zz_wcvt<<<dim3(CDIV(FINP*FINP,256)), 256, 0, stream>>>(W2, W2T, FIN, FIN, FINP, FINP);
  for (int l = 0; l < 2; ++l) {
    zz_wcvt<<<dim3(CDIV(480*160,256)), 256, 0, stream>>>(attn_in_w + (size_t)l*DT*3*DT,
        WTqkv + (size_t)l*76800, DT, 3*DT, DT, 3*DT);
    zz_wcvt<<<dim3(CDIV(160*160,256)), 256, 0, stream>>>(attn_out_w + (size_t)l*DT*DT,
        WTao + (size_t)l*25600, DT, DT, DT, DT);
    zz_wcvt<<<dim3(CDIV(128*160,256)), 256, 0, stream>>>(ff1_w + (size_t)l*DT*NHID,
        WTf1 + (size_t)l*20480, DT, NHID, DT, NHID);
    zz_wcvt<<<dim3(CDIV(160*128,256)), 256, 0, stream>>>(ff2_w + (size_t)l*NHID*DT,
        WTf2 + (size_t)l*20480, NHID, DT, NHID, DT);
  }

  for (int ch = 0; ch < NCH; ++ch) {
    int b0 = ch * CB;
    // ---- GAT stack (chunk) ----
    zz_build_x<<<dim3(CDIV(CB*DI*S_LEN,256)), 256, 0, stream>>>(src, R_u, Xc, b0, CB);
    zz_zeropad<<<dim3(CDIV(CB*DI,256)), 256, 0, stream>>>(Xc, CB);
    zz_gat_mfma<<<dim3(2, CB), 256, 0, stream>>>(Xc, W1T, XPc, CB);
    zz_gat_attvec<<<dim3(DI, CB), 64, 0, stream>>>(XPc, a1_s, a1_d, SS, SD, b0);
    zz_gat_alpha<<<dim3(CB), 256, 0, stream>>>(SS, SD, (const float*)nullptr, A1, b0);
    zz_gat_apply<<<dim3(4, CB), 256, 0, stream>>>(A1, XPc, H1c, 0, b0, CB);
    zz_zeropad<<<dim3(CDIV(CB*DI,256)), 256, 0, stream>>>(H1c, CB);
    zz_gat_mfma<<<dim3(2, CB), 256, 0, stream>>>(H1c, W2T, XPc, CB);
    zz_gat_attvec<<<dim3(DI, CB), 64, 0, stream>>>(XPc, a2_s, a2_d, SS, SD, b0);
    zz_gat_alpha<<<dim3(CB), 256, 0, stream>>>(SS, SD, A1, A2, b0);
    zz_gat_apply<<<dim3(4, CB), 256, 0, stream>>>(A2, XPc, XCH, 1, b0, CB);
    zz_pe<<<dim3(CDIV(CB*S_LEN*16,256)), 256, 0, stream>>>(times, XCH, b0, CB);

    // ---- transformer (chunk) ----
    for (int l = 0; l < 2; ++l) {
      zz_mgemm<0,0><<<dim3(CDIV(NTOKC,64)), 256, 0, stream>>>(XCH,
          WTqkv + (size_t)l*76800, attn_in_b + l*3*DT, nullptr, QKVc, NTOKC, 3*DT, DT);
      zz_fattn<<<dim3(CB*NH), 256, 0, stream>>>(QKVc, lengths, OAc, b0, CB);
      zz_mgemm<0,1><<<dim3(CDIV(NTOKC,64)), 256, 0, stream>>>(OAc,
          WTao + (size_t)l*25600, attn_out_b + l*DT, XCH, Tc, NTOKC, DT, DT);
      zz_ln<<<dim3(CDIV(NTOKC,4)), 256, 0, stream>>>(Tc, ln1_g + l*DT, ln1_b + l*DT, XCH, NTOKC);
      zz_mgemm<1,0><<<dim3(CDIV(NTOKC,64)), 256, 0, stream>>>(XCH,
          WTf1 + (size_t)l*20480, ff1_b + l*NHID, nullptr, Yc, NTOKC, NHID, DT);
      zz_mgemm<0,1><<<dim3(CDIV(NTOKC,64)), 256, 0, stream>>>(Yc,
          WTf2 + (size_t)l*20480, ff2_b + l*DT, XCH, Tc, NTOKC, DT, NHID);
      zz_ln<<<dim3(CDIV(NTOKC,4)), 256, 0, stream>>>(Tc, ln2_g + l*DT, ln2_b + l*DT, XCH, NTOKC);
    }

    zz_agg<<<dim3(CB), 256, 0, stream>>>(XCH, lengths, EMB, FEAT, b0, CB);
  }

  // ---- distance from alpha2 (full batch) ----
  zz_sq<<<dim3(NB), 64, 0, stream>>>(A2, SQB);
  zz_dist<<<dim3(8, 8), 256, 0, stream>>>(A2, SQB, DSUM);
  zz_dist_fin<<<1, 1, 0, stream>>>(DSUM, (float*)d_out + 1024);

  // ---- head (f32, tiny) ----
  zz_gemm<1,0><<<dim3(CDIV(DFIN,128), CDIV(NB,64)), 256, 0, stream>>>(FEAT, mlp1_w, mlp1_b,
      nullptr, FFEAT, NB, DFIN, DFIN);
  zz_gemm<0,0><<<dim3(1, CDIV(NB,64)), 256, 0, stream>>>(FFEAT, mlp2_w, mlp2_b,
      nullptr, (float*)d_out, NB, 2, DFIN);
}

// Round 10
// 2967.879 us; speedup vs baseline: 1.3433x; 1.0215x over previous
//
#include <hip/hip_runtime.h>
#include <hip/hip_bf16.h>
#include <math.h>

#define S_LEN 215
#define NB    512
#define DI    36
#define DMODEL 144
#define DT    160
#define NH    4
#define DH    40
#define NHID  128
#define FIN   860
#define FINP  864          // K-padded
#define DFIN  196
#define TP    226          // LDS t-stride (shorts): 113 dwords per row (odd -> conflict-free)
#define CDIV(a,b) (((a)+(b)-1)/(b))

typedef __attribute__((ext_vector_type(8))) short bf16x8;
typedef __attribute__((ext_vector_type(4))) float f32x4;

__device__ inline bf16x8 zz_cvt8(const float* __restrict__ p) {
  float4 lo = *(const float4*)p;
  float4 hi = *(const float4*)(p + 4);
  union { bf16x8 v; __hip_bfloat16 h[8]; } u;
  u.h[0] = __float2bfloat16(lo.x); u.h[1] = __float2bfloat16(lo.y);
  u.h[2] = __float2bfloat16(lo.z); u.h[3] = __float2bfloat16(lo.w);
  u.h[4] = __float2bfloat16(hi.x); u.h[5] = __float2bfloat16(hi.y);
  u.h[6] = __float2bfloat16(hi.z); u.h[7] = __float2bfloat16(hi.w);
  return u.v;
}

__device__ inline bf16x8 zz_cvt8a(const float t[8]) {
  union { bf16x8 v; __hip_bfloat16 h[8]; } u;
  #pragma unroll
  for (int i = 0; i < 8; ++i) u.h[i] = __float2bfloat16(t[i]);
  return u.v;
}

// ---------------- weight transpose + bf16 convert: WT[n][k] = bf16(W[k][n]) ----------------
__global__ __launch_bounds__(256) void zz_wcvt(const float* __restrict__ W,
    short* __restrict__ WT, int K, int N, int Kpad, int Npad)
{
  int idx = blockIdx.x*256 + threadIdx.x;
  if (idx >= Npad*Kpad) return;
  int n = idx / Kpad, k = idx % Kpad;
  float v = (n < N && k < K) ? W[(size_t)k*N + n] : 0.f;
  union { __hip_bfloat16 h; short s; } c;
  c.h = __float2bfloat16(v);
  WT[idx] = c.s;
}

// ---------------- build x chunk ----------------
__global__ __launch_bounds__(256) void zz_build_x(const float* __restrict__ src,
    const float* __restrict__ R_u, float* __restrict__ X, int b0, int CB)
{
  int idx = blockIdx.x*256 + threadIdx.x;           // (bl,i,s)
  if (idx >= CB*DI*S_LEN) return;
  int s = idx % S_LEN; int t = idx / S_LEN; int i = t % DI; int bl = t / DI;
  float v = src[((size_t)s*NB + b0 + bl)*(2*DI) + i];
  float4 r = *(const float4*)(R_u + i*4);
  float4 o;
  o.x = fmaxf(v*r.x, 0.f); o.y = fmaxf(v*r.y, 0.f);
  o.z = fmaxf(v*r.z, 0.f); o.w = fmaxf(v*r.w, 0.f);
  *(float4*)(X + (size_t)(bl*DI + i)*FINP + s*4) = o;
}

// ---------------- zero pad cols 860..863 ----------------
__global__ __launch_bounds__(256) void zz_zeropad(float* __restrict__ buf, int CB)
{
  int idx = blockIdx.x*256 + threadIdx.x;
  if (idx >= CB*DI) return;
  float4 z = {0.f,0.f,0.f,0.f};
  *(float4*)(buf + (size_t)idx*FINP + FIN) = z;
}

// ---------------- positional encoding ----------------
__global__ __launch_bounds__(256) void zz_pe(const float* __restrict__ times,
    float* __restrict__ XCH, int b0, int CB)
{
  int idx = blockIdx.x*256 + threadIdx.x;           // (tl, k)
  if (idx >= CB*S_LEN*16) return;
  int k = idx & 15; int tl = idx >> 4;
  int bl = tl % CB; int s = tl / CB;
  int j = k & 7;
  float ts = powf(215.f, (float)j * (1.f/7.f)) * 100.f;
  float sc = times[(size_t)s*NB + b0 + bl] / ts;
  XCH[(size_t)tl*DT + DMODEL + k] = (k < 8) ? sinf(sc) : cosf(sc);
}

// ---------------- emb ----------------
__global__ __launch_bounds__(256) void zz_emb(const float* __restrict__ st,
    const float* __restrict__ w, const float* __restrict__ bias, float* __restrict__ emb)
{
  int idx = blockIdx.x*256 + threadIdx.x;
  if (idx >= NB*DI) return;
  int b = idx / DI, k = idx % DI;
  float acc = bias[k];
  #pragma unroll
  for (int j = 0; j < 9; ++j) acc = fmaf(st[b*9 + j], w[j*DI + k], acc);
  emb[idx] = acc;
}

// ---------------- per-row dots ----------------
__global__ __launch_bounds__(64) void zz_gat_attvec(const float* __restrict__ XP,
    const float* __restrict__ a_s, const float* __restrict__ a_d,
    float* __restrict__ ss, float* __restrict__ sd, int b0)
{
  int i = blockIdx.x, bl = blockIdx.y, lane = threadIdx.x;
  const float* row = XP + ((size_t)bl*DI + i)*FINP;
  float ps = 0.f, pd = 0.f;
  for (int k = lane; k < FIN; k += 64) {
    float v = row[k];
    ps = fmaf(v, a_s[k], ps);
    pd = fmaf(v, a_d[k], pd);
  }
  for (int off = 32; off; off >>= 1) { ps += __shfl_xor(ps, off); pd += __shfl_xor(pd, off); }
  if (!lane) { ss[(b0 + bl)*DI + i] = ps; sd[(b0 + bl)*DI + i] = pd; }
}

// ---------------- alpha softmax ----------------
__global__ __launch_bounds__(256) void zz_gat_alpha(const float* __restrict__ ss,
    const float* __restrict__ sd, const float* __restrict__ edge, float* __restrict__ alpha, int b0)
{
  int b = b0 + blockIdx.x;
  int wv = threadIdx.x >> 6, lane = threadIdx.x & 63;
  for (int i = wv; i < DI; i += 4) {
    float di = sd[b*DI + i];
    float e = -3e38f, x = 0.f;
    if (lane < DI) {
      x = di + ss[b*DI + lane];
      x = (x >= 0.f) ? x : 0.2f*x;
      e = x;
    }
    float m = e;
    for (int off = 32; off; off >>= 1) m = fmaxf(m, __shfl_xor(m, off));
    float p = (lane < DI) ? expf(e - m) : 0.f;
    float s = p;
    for (int off = 32; off; off >>= 1) s += __shfl_xor(s, off);
    if (lane < DI) {
      float a = p / s;
      size_t o = ((size_t)b*DI + i)*DI + lane;
      if (edge) a *= edge[o];
      alpha[o] = a;
    }
  }
}

// ---------------- gat apply ----------------
__global__ __launch_bounds__(256) void zz_gat_apply(const float* __restrict__ alpha,
    const float* __restrict__ XP, float* __restrict__ out, int mode, int b0, int CB)
{
  __shared__ float Al[DI][37];
  __shared__ float Xs[DI][260];
  int bl = blockIdx.y, n0 = blockIdx.x * 256;
  int tid = threadIdx.x;
  int nt = tid & 63, mg = tid >> 6;
  const float* ab = alpha + ((size_t)(b0 + bl))*DI*DI;
  for (int i = tid; i < DI*DI; i += 256) Al[i/DI][i%DI] = ab[i];
  const float* XPb = XP + (size_t)bl*DI*FINP;
  for (int i = tid; i < DI*256; i += 256) {
    int k = i >> 8, nn = i & 255, gn = n0 + nn;
    Xs[k][nn] = (gn < FIN) ? XPb[(size_t)k*FINP + gn] : 0.f;
  }
  __syncthreads();
  float acc[9][4] = {};
  #pragma unroll 4
  for (int k = 0; k < DI; ++k) {
    float4 x4 = *(const float4*)&Xs[k][nt*4];
    float xb[4] = {x4.x, x4.y, x4.z, x4.w};
    #pragma unroll
    for (int m = 0; m < 9; ++m) {
      float av = Al[mg*9 + m][k];
      #pragma unroll
      for (int v = 0; v < 4; ++v) acc[m][v] = fmaf(av, xb[v], acc[m][v]);
    }
  }
  int gn = n0 + nt*4;
  if (gn < FIN) {
    if (mode == 0) {
      float* ob = out + (size_t)bl*DI*FINP;
      #pragma unroll
      for (int m = 0; m < 9; ++m) {
        float4 o4 = {acc[m][0], acc[m][1], acc[m][2], acc[m][3]};
        *(float4*)(ob + (size_t)(mg*9 + m)*FINP + gn) = o4;
      }
    } else {
      int s = gn >> 2;
      float* op = out + ((size_t)s*CB + bl)*DT;
      #pragma unroll
      for (int m = 0; m < 9; ++m) {
        float4 o4 = {acc[m][0], acc[m][1], acc[m][2], acc[m][3]};
        *(float4*)(op + (mg*9 + m)*4) = o4;
      }
    }
  }
}

// ---------------- distance helpers ----------------
__global__ __launch_bounds__(64) void zz_sq(const float* __restrict__ A, float* __restrict__ sq)
{
  int i = blockIdx.x, lane = threadIdx.x;
  const float* row = A + (size_t)i*(DI*DI);
  float s = 0.f;
  for (int k = lane; k < DI*DI; k += 64) { float v = row[k]; s = fmaf(v, v, s); }
  for (int off = 32; off; off >>= 1) s += __shfl_xor(s, off);
  if (!lane) sq[i] = s;
}

__global__ __launch_bounds__(256) void zz_dist(const float* __restrict__ A,
    const float* __restrict__ sq, float* __restrict__ dsum)
{
  __shared__ float Ai[64][65], Aj[64][65];
  __shared__ float red[256];
  int i0 = blockIdx.y*64, j0 = blockIdx.x*64;
  int tid = threadIdx.x, tx = tid % 16, ty = tid / 16;
  float acc[4][4] = {};
  for (int k0 = 0; k0 < DI*DI; k0 += 64) {
    for (int t = tid; t < 64*64; t += 256) {
      int r = t >> 6, kk = t & 63, gk = k0 + kk;
      float vi = 0.f, vj = 0.f;
      if (gk < DI*DI) {
        vi = A[(size_t)(i0 + r)*(DI*DI) + gk];
        vj = A[(size_t)(j0 + r)*(DI*DI) + gk];
      }
      Ai[r][kk] = vi; Aj[r][kk] = vj;
    }
    __syncthreads();
    #pragma unroll 8
    for (int kk = 0; kk < 64; ++kk) {
      float a[4], bb[4];
      #pragma unroll
      for (int u = 0; u < 4; ++u) a[u]  = Ai[ty*4 + u][kk];
      #pragma unroll
      for (int u = 0; u < 4; ++u) bb[u] = Aj[tx*4 + u][kk];
      #pragma unroll
      for (int u = 0; u < 4; ++u)
        #pragma unroll
        for (int v = 0; v < 4; ++v) acc[u][v] = fmaf(a[u], bb[v], acc[u][v]);
    }
    __syncthreads();
  }
  float s = 0.f;
  #pragma unroll
  for (int u = 0; u < 4; ++u)
    #pragma unroll
    for (int v = 0; v < 4; ++v) {
      float d2 = sq[i0 + ty*4 + u] + sq[j0 + tx*4 + v] - 2.f*acc[u][v];
      d2 = fmaxf(d2, 0.f);
      s += sqrtf(d2 + 1e-12f);
    }
  red[tid] = s; __syncthreads();
  for (int st = 128; st; st >>= 1) { if (tid < st) red[tid] += red[tid + st]; __syncthreads(); }
  if (!tid) atomicAdd(dsum, red[0]);
}

__global__ void zz_dist_fin(const float* dsum, float* out)
{
  out[0] = dsum[0] * (1.f/((float)NB*(float)NB));
}

// ---------------- token GEMM via MFMA (n-chunked grid: blockIdx.y covers ntpc n-pairs) ----------------
template<int RELU, int RES>
__global__ __launch_bounds__(256) void zz_mgemm(const float* __restrict__ A,
    const short* __restrict__ BT, const float* __restrict__ bias,
    const float* __restrict__ res, float* __restrict__ C, int M, int N, int K, int ntpc)
{
  int wave = threadIdx.x >> 6, lane = threadIdx.x & 63;
  int m0 = blockIdx.x*64 + wave*16;
  if (m0 >= M) return;
  int r = lane & 15, g = lane >> 4;
  int arow = m0 + r; if (arow >= M) arow = M - 1;
  const float* Ap = A + (size_t)arow*K + g*8;
  int NP = N >> 5;
  int p0 = blockIdx.y * ntpc;
  int p1 = p0 + ntpc; if (p1 > NP) p1 = NP;
  for (int ntp = p0; ntp < p1; ++ntp) {
    int n0 = ntp*32;
    const short* B0 = BT + (size_t)(n0 + r)*K + g*8;
    const short* B1 = B0 + (size_t)16*K;
    f32x4 acc0 = {0.f,0.f,0.f,0.f}, acc1 = {0.f,0.f,0.f,0.f};
    #pragma unroll 5
    for (int k0 = 0; k0 < K; k0 += 32) {
      bf16x8 af = zz_cvt8(Ap + k0);
      bf16x8 b0 = *(const bf16x8*)(B0 + k0);
      bf16x8 b1 = *(const bf16x8*)(B1 + k0);
      acc0 = __builtin_amdgcn_mfma_f32_16x16x32_bf16(af, b0, acc0, 0, 0, 0);
      acc1 = __builtin_amdgcn_mfma_f32_16x16x32_bf16(af, b1, acc1, 0, 0, 0);
    }
    #pragma unroll
    for (int j = 0; j < 4; ++j) {
      int row = m0 + g*4 + j;
      if (row >= M) continue;
      int c0 = n0 + r, c1 = n0 + 16 + r;
      float v0 = acc0[j] + bias[c0];
      float v1 = acc1[j] + bias[c1];
      if (RES) { v0 += res[(size_t)row*N + c0]; v1 += res[(size_t)row*N + c1]; }
      if (RELU) { v0 = fmaxf(v0, 0.f); v1 = fmaxf(v1, 0.f); }
      C[(size_t)row*N + c0] = v0;
      C[(size_t)row*N + c1] = v1;
    }
  }
}

// ---------------- f32 tiled GEMM (head) ----------------
template<int RELU, int RES>
__global__ __launch_bounds__(256) void zz_gemm(const float* __restrict__ A,
    const float* __restrict__ Bw, const float* __restrict__ bias,
    const float* __restrict__ res, float* __restrict__ C, int M, int N, int K)
{
  __shared__ float As[64][33];
  __shared__ float Bs[32][136];
  int m0 = blockIdx.y*64, n0 = blockIdx.x*128;
  int tid = threadIdx.x, tx = tid & 15, ty = tid >> 4;
  float acc[4][8] = {};
  for (int k0 = 0; k0 < K; k0 += 32) {
    for (int i = tid; i < 64*32; i += 256) {
      int rr = i >> 5, kk = i & 31;
      int gm = m0 + rr, gk = k0 + kk;
      As[rr][kk] = (gm < M && gk < K) ? A[(size_t)gm*K + gk] : 0.f;
    }
    for (int i = tid; i < 32*128; i += 256) {
      int kk = i >> 7, n = i & 127;
      int gk = k0 + kk, gn = n0 + n;
      Bs[kk][n] = (gk < K && gn < N) ? Bw[(size_t)gk*N + gn] : 0.f;
    }
    __syncthreads();
    #pragma unroll 4
    for (int kk = 0; kk < 32; ++kk) {
      float a[4];
      #pragma unroll
      for (int u = 0; u < 4; ++u) a[u] = As[ty*4 + u][kk];
      float4 b0 = *(const float4*)&Bs[kk][tx*8];
      float4 b1 = *(const float4*)&Bs[kk][tx*8 + 4];
      float b[8] = {b0.x,b0.y,b0.z,b0.w,b1.x,b1.y,b1.z,b1.w};
      #pragma unroll
      for (int u = 0; u < 4; ++u)
        #pragma unroll
        for (int v = 0; v < 8; ++v) acc[u][v] = fmaf(a[u], b[v], acc[u][v]);
    }
    __syncthreads();
  }
  #pragma unroll
  for (int u = 0; u < 4; ++u) {
    int gm = m0 + ty*4 + u;
    if (gm >= M) continue;
    #pragma unroll
    for (int v = 0; v < 8; ++v) {
      int gn = n0 + tx*8 + v;
      if (gn >= N) continue;
      float val = acc[u][v] + bias[gn];
      if (RES) val += res[(size_t)gm*N + gn];
      if (RELU) val = fmaxf(val, 0.f);
      C[(size_t)gm*N + gn] = val;
    }
  }
}

// ---------------- fused MFMA attention v2: one block per (bl,h); K,V staged once ----------------
__global__ __launch_bounds__(256) void zz_fattn(const float* __restrict__ QKV,
    const int* __restrict__ lengths, float* __restrict__ O, int b0, int CB)
{
  __shared__ short K_lds[224][66];
  __shared__ short VT[48][TP];
  __shared__ short PT[4][16][TP];
  const float LOG2E = 1.44269504088896f;
  int bh = blockIdx.x, bl = bh >> 2, h = bh & 3;
  int tid = threadIdx.x, wave = tid >> 6, lane = tid & 63;
  int len = lengths[b0 + bl];

  for (int i = tid; i < 224*64; i += 256) {
    int t = i >> 6, d = i & 63;
    float kv = 0.f, vv = 0.f;
    if (t < S_LEN && d < DH) {
      const float* base = QKV + ((size_t)t*CB + bl)*(3*DT) + DT + h*DH + d;
      kv = base[0];        // K
      vv = base[DT];       // V
    }
    union { __hip_bfloat16 hh; short s; } ck, cv;
    ck.hh = __float2bfloat16(kv);
    K_lds[t][d] = ck.s;
    if (d < 48) { cv.hh = __float2bfloat16(vv); VT[d][t] = cv.s; }
  }
  __syncthreads();

  int r = lane & 15, g = lane >> 4;
  for (int mt = wave; mt < 14; mt += 4) {
    int m0 = mt*16;
    int qrow = m0 + r; if (qrow > S_LEN-1) qrow = S_LEN-1;
    const float* qp = QKV + ((size_t)qrow*CB + bl)*(3*DT) + h*DH;
    bf16x8 qf0, qf1;
    {
      float t0[8], t1[8];
      #pragma unroll
      for (int u = 0; u < 8; ++u) t0[u] = qp[g*8 + u] * 0.15811388300841897f;
      #pragma unroll
      for (int u = 0; u < 8; ++u) t1[u] = (g == 0) ? qp[32 + u] * 0.15811388300841897f : 0.f;
      qf0 = zz_cvt8a(t0); qf1 = zz_cvt8a(t1);
    }
    f32x4 acc[14];
    #pragma unroll
    for (int nt = 0; nt < 14; ++nt) acc[nt] = (f32x4){0.f,0.f,0.f,0.f};
    #pragma unroll
    for (int nt = 0; nt < 14; ++nt) {
      int trow = nt*16 + r; if (trow > S_LEN-1) trow = S_LEN-1;
      bf16x8 b0 = *(const bf16x8*)&K_lds[trow][g*8];
      bf16x8 b1 = *(const bf16x8*)&K_lds[trow][32 + g*8];
      acc[nt] = __builtin_amdgcn_mfma_f32_16x16x32_bf16(qf0, b0, acc[nt], 0, 0, 0);
      acc[nt] = __builtin_amdgcn_mfma_f32_16x16x32_bf16(qf1, b1, acc[nt], 0, 0, 0);
    }
    #pragma unroll
    for (int j = 0; j < 4; ++j) {
      float mx = -3e38f;
      #pragma unroll
      for (int nt = 0; nt < 14; ++nt) {
        int t = nt*16 + r;
        float v = (t < len) ? acc[nt][j] : -1e9f;
        acc[nt][j] = v;
        mx = fmaxf(mx, v);
      }
      mx = fmaxf(mx, __shfl_xor(mx, 1));
      mx = fmaxf(mx, __shfl_xor(mx, 2));
      mx = fmaxf(mx, __shfl_xor(mx, 4));
      mx = fmaxf(mx, __shfl_xor(mx, 8));
      float sum = 0.f;
      #pragma unroll
      for (int nt = 0; nt < 14; ++nt) {
        float p = exp2f((acc[nt][j] - mx) * LOG2E);
        acc[nt][j] = p;
        sum += p;
      }
      sum += __shfl_xor(sum, 1);
      sum += __shfl_xor(sum, 2);
      sum += __shfl_xor(sum, 4);
      sum += __shfl_xor(sum, 8);
      float inv = 1.f / sum;
      #pragma unroll
      for (int nt = 0; nt < 14; ++nt) {
        union { __hip_bfloat16 hh; short s; } c;
        c.hh = __float2bfloat16(acc[nt][j] * inv);
        PT[wave][g*4 + j][nt*16 + r] = c.s;
      }
    }
    f32x4 oacc0 = {0.f,0.f,0.f,0.f}, oacc1 = {0.f,0.f,0.f,0.f}, oacc2 = {0.f,0.f,0.f,0.f};
    #pragma unroll
    for (int ks = 0; ks < 7; ++ks) {
      bf16x8 pa = *(const bf16x8*)&PT[wave][r][ks*32 + g*8];
      bf16x8 v0 = *(const bf16x8*)&VT[r][ks*32 + g*8];
      bf16x8 v1 = *(const bf16x8*)&VT[16 + r][ks*32 + g*8];
      bf16x8 v2 = *(const bf16x8*)&VT[32 + r][ks*32 + g*8];
      oacc0 = __builtin_amdgcn_mfma_f32_16x16x32_bf16(pa, v0, oacc0, 0, 0, 0);
      oacc1 = __builtin_amdgcn_mfma_f32_16x16x32_bf16(pa, v1, oacc1, 0, 0, 0);
      oacc2 = __builtin_amdgcn_mfma_f32_16x16x32_bf16(pa, v2, oacc2, 0, 0, 0);
    }
    #pragma unroll
    for (int j = 0; j < 4; ++j) {
      int row = m0 + g*4 + j;
      if (row >= S_LEN) continue;
      float* op = O + ((size_t)row*CB + bl)*DT + h*DH;
      op[r] = oacc0[j];
      op[16 + r] = oacc1[j];
      if (32 + r < DH) op[32 + r] = oacc2[j];
    }
  }
}

// ---------------- layernorm ----------------
__global__ __launch_bounds__(256) void zz_ln(const float* __restrict__ X,
    const float* __restrict__ g, const float* __restrict__ bt, float* __restrict__ Y, int ntok)
{
  int tok = blockIdx.x*4 + (threadIdx.x >> 6);
  if (tok >= ntok) return;
  int lane = threadIdx.x & 63;
  const float* x = X + (size_t)tok*DT;
  float v0 = x[lane], v1 = x[lane + 64];
  float v2 = (lane < 32) ? x[lane + 128] : 0.f;
  float s = v0 + v1 + v2;
  for (int off = 32; off; off >>= 1) s += __shfl_xor(s, off);
  float mean = s * (1.f/160.f);
  float d0 = v0 - mean, d1 = v1 - mean, d2 = (lane < 32) ? (v2 - mean) : 0.f;
  float q = d0*d0 + d1*d1 + d2*d2;
  for (int off = 32; off; off >>= 1) q += __shfl_xor(q, off);
  float inv = 1.f / sqrtf(q * (1.f/160.f) + 1e-5f);
  float* y = Y + (size_t)tok*DT;
  y[lane]      = d0*inv*g[lane]      + bt[lane];
  y[lane + 64] = d1*inv*g[lane + 64] + bt[lane + 64];
  if (lane < 32) y[lane + 128] = d2*inv*g[lane + 128] + bt[lane + 128];
}

// ---------------- masked mean + feat concat ----------------
__global__ __launch_bounds__(256) void zz_agg(const float* __restrict__ XCH,
    const int* __restrict__ lengths, const float* __restrict__ emb, float* __restrict__ feat,
    int b0, int CB)
{
  int bl = blockIdx.x, tid = threadIdx.x;
  int b = b0 + bl;
  int len = lengths[b];
  if (tid < DT) {
    float acc = 0.f;
    for (int s = 0; s < len; ++s) acc += XCH[((size_t)s*CB + bl)*DT + tid];
    feat[(size_t)b*DFIN + tid] = acc / (float)(len + 1);
  } else if (tid < DFIN) {
    feat[(size_t)b*DFIN + tid] = emb[b*DI + (tid - DT)];
  }
}

// ======================================================================
extern "C" void kernel_launch(void* const* d_in, const int* in_sizes, int n_in,
                              void* d_out, int out_size, void* d_ws, size_t ws_size,
                              hipStream_t stream)
{
  (void)in_sizes; (void)n_in; (void)out_size;
  const float* src     = (const float*)d_in[0];
  const float* statc   = (const float*)d_in[1];
  const float* times   = (const float*)d_in[2];
  const int*   lengths = (const int*)  d_in[3];
  const float* R_u     = (const float*)d_in[4];
  const float* emb_w   = (const float*)d_in[5];
  const float* emb_b   = (const float*)d_in[6];
  const float* W1      = (const float*)d_in[7];
  const float* a1_s    = (const float*)d_in[8];
  const float* a1_d    = (const float*)d_in[9];
  const float* W2      = (const float*)d_in[10];
  const float* a2_s    = (const float*)d_in[11];
  const float* a2_d    = (const float*)d_in[12];
  const float* attn_in_w  = (const float*)d_in[13];
  const float* attn_in_b  = (const float*)d_in[14];
  const float* attn_out_w = (const float*)d_in[15];
  const float* attn_out_b = (const float*)d_in[16];
  const float* ff1_w = (const float*)d_in[17];
  const float* ff1_b = (const float*)d_in[18];
  const float* ff2_w = (const float*)d_in[19];
  const float* ff2_b = (const float*)d_in[20];
  const float* ln1_g = (const float*)d_in[21];
  const float* ln1_b = (const float*)d_in[22];
  const float* ln2_g = (const float*)d_in[23];
  const float* ln2_b = (const float*)d_in[24];
  const float* mlp1_w = (const float*)d_in[25];
  const float* mlp1_b = (const float*)d_in[26];
  const float* mlp2_w = (const float*)d_in[27];
  const float* mlp2_b = (const float*)d_in[28];

  // ---- small persistent buffers (floats) ----
  float* ws = (float*)d_ws;
  float* A1    = ws;                 // 663,552
  float* A2    = ws + 663552;        // 663,552
  float* SS    = ws + 1327104;       // 18,432
  float* SD    = ws + 1345536;       // 18,432
  float* SQB   = ws + 1363968;       // 512
  float* DSUM  = ws + 1364480;       // 64
  float* EMB   = ws + 1364544;       // 18,432
  float* FEAT  = ws + 1382976;       // 100,352
  float* FFEAT = ws + 1483328;       // 100,352
  float* ZEROB = ws + 1583680;       // 896 (zeroed bias)
  // bf16 weight area (shorts), 16B-aligned
  short* wb = (short*)(ws + 1584576);
  short* W1T   = wb;                 // 746,496
  short* W2T   = wb + 746496;        // 746,496
  short* WTqkv = wb + 1492992;       // 153,600
  short* WTao  = wb + 1646592;       // 51,200
  short* WTf1  = wb + 1697792;       // 40,960
  short* WTf2  = wb + 1738752;       // 40,960
  const size_t CHBASE = 1584576 + 889856;   // = 2,474,432 floats
  float* CH = ws + CHBASE;

  // ---- pick largest chunk size that fits ws_size ----
  int CB = 8;
  const int cands[7] = {512, 256, 128, 64, 32, 16, 8};
  for (int c = 0; c < 7; ++c) {
    size_t need = 4ull * (CHBASE + 233920ull * (size_t)cands[c]);
    if (need <= ws_size) { CB = cands[c]; break; }
  }
  const int NCH = NB / CB;
  const int NTOKC = S_LEN * CB;

  float* XCH = CH;                         // 34,400*CB
  float* R0  = CH + (size_t)34400*CB;
  float* Xc  = R0;                         // 31,104*CB
  float* XPc = R0 + (size_t)31104*CB;      // 31,104*CB
  float* H1c = R0 + (size_t)62208*CB;      // 31,104*CB
  float* QKVc = R0;                        // 103,200*CB
  float* OAc  = R0 + (size_t)103200*CB;    // 34,400*CB
  float* Tc   = R0 + (size_t)137600*CB;    // 34,400*CB
  float* Yc   = R0 + (size_t)172000*CB;    // 27,520*CB

  hipMemsetAsync(DSUM, 0, 4, stream);
  hipMemsetAsync(ZEROB, 0, 896*4, stream);
  zz_emb<<<dim3(CDIV(NB*DI,256)), 256, 0, stream>>>(statc, emb_w, emb_b, EMB);

  // ---- one-time weight transpose+bf16 conversions ----
  zz_wcvt<<<dim3(CDIV(FINP*FINP,256)), 256, 0, stream>>>(W1, W1T, FIN, FIN, FINP, FINP);
  zz_wcvt<<<dim3(CDIV(FINP*FINP,256)), 256, 0, stream>>>(W2, W2T, FIN, FIN, FINP, FINP);
  for (int l = 0; l < 2; ++l) {
    zz_wcvt<<<dim3(CDIV(480*160,256)), 256, 0, stream>>>(attn_in_w + (size_t)l*DT*3*DT,
        WTqkv + (size_t)l*76800, DT, 3*DT, DT, 3*DT);
    zz_wcvt<<<dim3(CDIV(160*160,256)), 256, 0, stream>>>(attn_out_w + (size_t)l*DT*DT,
        WTao + (size_t)l*25600, DT, DT, DT, DT);
    zz_wcvt<<<dim3(CDIV(128*160,256)), 256, 0, stream>>>(ff1_w + (size_t)l*DT*NHID,
        WTf1 + (size_t)l*20480, DT, NHID, DT, NHID);
    zz_wcvt<<<dim3(CDIV(160*128,256)), 256, 0, stream>>>(ff2_w + (size_t)l*NHID*DT,
        WTf2 + (size_t)l*20480, NHID, DT, NHID, DT);
  }

  for (int ch = 0; ch < NCH; ++ch) {
    int b0 = ch * CB;
    // ---- GAT stack (chunk) ----
    zz_build_x<<<dim3(CDIV(CB*DI*S_LEN,256)), 256, 0, stream>>>(src, R_u, Xc, b0, CB);
    zz_zeropad<<<dim3(CDIV(CB*DI,256)), 256, 0, stream>>>(Xc, CB);
    // batched GAT GEMM: XP(CB*36 x 864) = X @ W1 ; grid (m=72, nchunk=7) -> same-A blocks share XCD
    zz_mgemm<0,0><<<dim3(CDIV(CB*DI,64), 7), 256, 0, stream>>>(Xc, W1T, ZEROB, nullptr,
        XPc, CB*DI, FINP, FINP, 4);
    zz_gat_attvec<<<dim3(DI, CB), 64, 0, stream>>>(XPc, a1_s, a1_d, SS, SD, b0);
    zz_gat_alpha<<<dim3(CB), 256, 0, stream>>>(SS, SD, (const float*)nullptr, A1, b0);
    zz_gat_apply<<<dim3(4, CB), 256, 0, stream>>>(A1, XPc, H1c, 0, b0, CB);
    zz_zeropad<<<dim3(CDIV(CB*DI,256)), 256, 0, stream>>>(H1c, CB);
    zz_mgemm<0,0><<<dim3(CDIV(CB*DI,64), 7), 256, 0, stream>>>(H1c, W2T, ZEROB, nullptr,
        XPc, CB*DI, FINP, FINP, 4);
    zz_gat_attvec<<<dim3(DI, CB), 64, 0, stream>>>(XPc, a2_s, a2_d, SS, SD, b0);
    zz_gat_alpha<<<dim3(CB), 256, 0, stream>>>(SS, SD, A1, A2, b0);
    zz_gat_apply<<<dim3(4, CB), 256, 0, stream>>>(A2, XPc, XCH, 1, b0, CB);
    zz_pe<<<dim3(CDIV(CB*S_LEN*16,256)), 256, 0, stream>>>(times, XCH, b0, CB);

    // ---- transformer (chunk) ----
    for (int l = 0; l < 2; ++l) {
      zz_mgemm<0,0><<<dim3(CDIV(NTOKC,64), 1), 256, 0, stream>>>(XCH,
          WTqkv + (size_t)l*76800, attn_in_b + l*3*DT, nullptr, QKVc, NTOKC, 3*DT, DT, 15);
      zz_fattn<<<dim3(CB*NH), 256, 0, stream>>>(QKVc, lengths, OAc, b0, CB);
      zz_mgemm<0,1><<<dim3(CDIV(NTOKC,64), 1), 256, 0, stream>>>(OAc,
          WTao + (size_t)l*25600, attn_out_b + l*DT, XCH, Tc, NTOKC, DT, DT, 5);
      zz_ln<<<dim3(CDIV(NTOKC,4)), 256, 0, stream>>>(Tc, ln1_g + l*DT, ln1_b + l*DT, XCH, NTOKC);
      zz_mgemm<1,0><<<dim3(CDIV(NTOKC,64), 1), 256, 0, stream>>>(XCH,
          WTf1 + (size_t)l*20480, ff1_b + l*NHID, nullptr, Yc, NTOKC, NHID, DT, 4);
      zz_mgemm<0,1><<<dim3(CDIV(NTOKC,64), 1), 256, 0, stream>>>(Yc,
          WTf2 + (size_t)l*20480, ff2_b + l*DT, XCH, Tc, NTOKC, DT, NHID, 5);
      zz_ln<<<dim3(CDIV(NTOKC,4)), 256, 0, stream>>>(Tc, ln2_g + l*DT, ln2_b + l*DT, XCH, NTOKC);
    }

    zz_agg<<<dim3(CB), 256, 0, stream>>>(XCH, lengths, EMB, FEAT, b0, CB);
  }

  // ---- distance from alpha2 (full batch) ----
  zz_sq<<<dim3(NB), 64, 0, stream>>>(A2, SQB);
  zz_dist<<<dim3(8, 8), 256, 0, stream>>>(A2, SQB, DSUM);
  zz_dist_fin<<<1, 1, 0, stream>>>(DSUM, (float*)d_out + 1024);

  // ---- head (f32, tiny) ----
  zz_gemm<1,0><<<dim3(CDIV(DFIN,128), CDIV(NB,64)), 256, 0, stream>>>(FEAT, mlp1_w, mlp1_b,
      nullptr, FFEAT, NB, DFIN, DFIN);
  zz_gemm<0,0><<<dim3(1, CDIV(NB,64)), 256, 0, stream>>>(FFEAT, mlp2_w, mlp2_b,
      nullptr, (float*)d_out, NB, 2, DFIN);
}

// Round 11
// 2282.710 us; speedup vs baseline: 1.7465x; 1.3002x over previous
//
#include <hip/hip_runtime.h>
#include <hip/hip_bf16.h>
#include <math.h>

#define S_LEN 215
#define NB    512
#define DI    36
#define DMODEL 144
#define DT    160
#define NH    4
#define DH    40
#define NHID  128
#define FIN   860
#define FINP  864
#define DFIN  196
#define TP    226
#define CDIV(a,b) (((a)+(b)-1)/(b))

typedef __attribute__((ext_vector_type(8))) short bf16x8;
typedef __attribute__((ext_vector_type(4))) float f32x4;

__device__ inline short zz_bf(float v) {
  union { __hip_bfloat16 h; short s; } c; c.h = __float2bfloat16(v); return c.s;
}

// ---------------- weight transpose + bf16 convert: WT[n][k] = bf16(W[k][n] * (n<qcols?qs:1)) ----------------
__global__ __launch_bounds__(256) void zz_wcvt(const float* __restrict__ W,
    short* __restrict__ WT, int K, int N, int Kpad, int Npad, int qcols, float qs)
{
  int idx = blockIdx.x*256 + threadIdx.x;
  if (idx >= Npad*Kpad) return;
  int n = idx / Kpad, k = idx % Kpad;
  float v = (n < N && k < K) ? W[(size_t)k*N + n] : 0.f;
  if (n < qcols) v *= qs;
  WT[idx] = zz_bf(v);
}

// ---------------- scaled qkv bias: out[i] = b[i] * (i%480<160 ? qs : 1) ----------------
__global__ __launch_bounds__(256) void zz_biasq(const float* __restrict__ b, float* __restrict__ out)
{
  int i = blockIdx.x*256 + threadIdx.x;
  if (i >= 960) return;
  int c = i % 480;
  out[i] = b[i] * ((c < DT) ? 0.15811388300841897f : 1.f);
}

// ---------------- build x chunk -> bf16 [CB*36][864] ----------------
__global__ __launch_bounds__(256) void zz_build_x(const float* __restrict__ src,
    const float* __restrict__ R_u, short* __restrict__ X, int b0, int CB)
{
  int idx = blockIdx.x*256 + threadIdx.x;           // (bl,i,s)
  if (idx >= CB*DI*S_LEN) return;
  int s = idx % S_LEN; int t = idx / S_LEN; int i = t % DI; int bl = t / DI;
  float v = src[((size_t)s*NB + b0 + bl)*(2*DI) + i];
  float4 r = *(const float4*)(R_u + i*4);
  short4 o;
  o.x = zz_bf(fmaxf(v*r.x, 0.f)); o.y = zz_bf(fmaxf(v*r.y, 0.f));
  o.z = zz_bf(fmaxf(v*r.z, 0.f)); o.w = zz_bf(fmaxf(v*r.w, 0.f));
  *(short4*)(X + (size_t)(bl*DI + i)*FINP + s*4) = o;
}

// ---------------- zero pad cols 860..863 of bf16 buffer ----------------
__global__ __launch_bounds__(256) void zz_zeropad_bf(short* __restrict__ buf, int CB)
{
  int idx = blockIdx.x*256 + threadIdx.x;
  if (idx >= CB*DI) return;
  short4 z = {0,0,0,0};
  *(short4*)(buf + (size_t)idx*FINP + FIN) = z;
}

// ---------------- positional encoding (dual write f32 + bf16) ----------------
__global__ __launch_bounds__(256) void zz_pe(const float* __restrict__ times,
    float* __restrict__ XCH, short* __restrict__ XCHb, int b0, int CB)
{
  int idx = blockIdx.x*256 + threadIdx.x;           // (tl, k)
  if (idx >= CB*S_LEN*16) return;
  int k = idx & 15; int tl = idx >> 4;
  int bl = tl % CB; int s = tl / CB;
  int j = k & 7;
  float ts = powf(215.f, (float)j * (1.f/7.f)) * 100.f;
  float sc = times[(size_t)s*NB + b0 + bl] / ts;
  float v = (k < 8) ? sinf(sc) : cosf(sc);
  XCH[(size_t)tl*DT + DMODEL + k] = v;
  XCHb[(size_t)tl*DT + DMODEL + k] = zz_bf(v);
}

// ---------------- emb ----------------
__global__ __launch_bounds__(256) void zz_emb(const float* __restrict__ st,
    const float* __restrict__ w, const float* __restrict__ bias, float* __restrict__ emb)
{
  int idx = blockIdx.x*256 + threadIdx.x;
  if (idx >= NB*DI) return;
  int b = idx / DI, k = idx % DI;
  float acc = bias[k];
  #pragma unroll
  for (int j = 0; j < 9; ++j) acc = fmaf(st[b*9 + j], w[j*DI + k], acc);
  emb[idx] = acc;
}

// ---------------- per-row dots (XP f32 stride FINP) ----------------
__global__ __launch_bounds__(64) void zz_gat_attvec(const float* __restrict__ XP,
    const float* __restrict__ a_s, const float* __restrict__ a_d,
    float* __restrict__ ss, float* __restrict__ sd, int b0)
{
  int i = blockIdx.x, bl = blockIdx.y, lane = threadIdx.x;
  const float* row = XP + ((size_t)bl*DI + i)*FINP;
  float ps = 0.f, pd = 0.f;
  for (int k = lane; k < FIN; k += 64) {
    float v = row[k];
    ps = fmaf(v, a_s[k], ps);
    pd = fmaf(v, a_d[k], pd);
  }
  for (int off = 32; off; off >>= 1) { ps += __shfl_xor(ps, off); pd += __shfl_xor(pd, off); }
  if (!lane) { ss[(b0 + bl)*DI + i] = ps; sd[(b0 + bl)*DI + i] = pd; }
}

// ---------------- alpha softmax ----------------
__global__ __launch_bounds__(256) void zz_gat_alpha(const float* __restrict__ ss,
    const float* __restrict__ sd, const float* __restrict__ edge, float* __restrict__ alpha, int b0)
{
  int b = b0 + blockIdx.x;
  int wv = threadIdx.x >> 6, lane = threadIdx.x & 63;
  for (int i = wv; i < DI; i += 4) {
    float di = sd[b*DI + i];
    float e = -3e38f, x = 0.f;
    if (lane < DI) {
      x = di + ss[b*DI + lane];
      x = (x >= 0.f) ? x : 0.2f*x;
      e = x;
    }
    float m = e;
    for (int off = 32; off; off >>= 1) m = fmaxf(m, __shfl_xor(m, off));
    float p = (lane < DI) ? expf(e - m) : 0.f;
    float s = p;
    for (int off = 32; off; off >>= 1) s += __shfl_xor(s, off);
    if (lane < DI) {
      float a = p / s;
      size_t o = ((size_t)b*DI + i)*DI + lane;
      if (edge) a *= edge[o];
      alpha[o] = a;
    }
  }
}

// ---------------- gat apply: mode0 -> bf16 H1 ; mode1 -> XCH f32 + bf16 ----------------
__global__ __launch_bounds__(256) void zz_gat_apply(const float* __restrict__ alpha,
    const float* __restrict__ XP, float* __restrict__ outf, short* __restrict__ outb,
    int mode, int b0, int CB)
{
  __shared__ float Al[DI][37];
  __shared__ float Xs[DI][260];
  int bl = blockIdx.y, n0 = blockIdx.x * 256;
  int tid = threadIdx.x;
  int nt = tid & 63, mg = tid >> 6;
  const float* ab = alpha + ((size_t)(b0 + bl))*DI*DI;
  for (int i = tid; i < DI*DI; i += 256) Al[i/DI][i%DI] = ab[i];
  const float* XPb = XP + (size_t)bl*DI*FINP;
  for (int i = tid; i < DI*256; i += 256) {
    int k = i >> 8, nn = i & 255, gn = n0 + nn;
    Xs[k][nn] = (gn < FIN) ? XPb[(size_t)k*FINP + gn] : 0.f;
  }
  __syncthreads();
  float acc[9][4] = {};
  #pragma unroll 4
  for (int k = 0; k < DI; ++k) {
    float4 x4 = *(const float4*)&Xs[k][nt*4];
    float xb[4] = {x4.x, x4.y, x4.z, x4.w};
    #pragma unroll
    for (int m = 0; m < 9; ++m) {
      float av = Al[mg*9 + m][k];
      #pragma unroll
      for (int v = 0; v < 4; ++v) acc[m][v] = fmaf(av, xb[v], acc[m][v]);
    }
  }
  int gn = n0 + nt*4;
  if (gn < FIN) {
    if (mode == 0) {
      short* ob = outb + (size_t)bl*DI*FINP;
      #pragma unroll
      for (int m = 0; m < 9; ++m) {
        short4 o4 = {zz_bf(acc[m][0]), zz_bf(acc[m][1]), zz_bf(acc[m][2]), zz_bf(acc[m][3])};
        *(short4*)(ob + (size_t)(mg*9 + m)*FINP + gn) = o4;
      }
    } else {
      int s = gn >> 2;
      float* op  = outf + ((size_t)s*CB + bl)*DT;
      short* opb = outb + ((size_t)s*CB + bl)*DT;
      #pragma unroll
      for (int m = 0; m < 9; ++m) {
        float4 o4 = {acc[m][0], acc[m][1], acc[m][2], acc[m][3]};
        *(float4*)(op + (mg*9 + m)*4) = o4;
        short4 s4 = {zz_bf(acc[m][0]), zz_bf(acc[m][1]), zz_bf(acc[m][2]), zz_bf(acc[m][3])};
        *(short4*)(opb + (mg*9 + m)*4) = s4;
      }
    }
  }
}

// ---------------- distance helpers ----------------
__global__ __launch_bounds__(64) void zz_sq(const float* __restrict__ A, float* __restrict__ sq)
{
  int i = blockIdx.x, lane = threadIdx.x;
  const float* row = A + (size_t)i*(DI*DI);
  float s = 0.f;
  for (int k = lane; k < DI*DI; k += 64) { float v = row[k]; s = fmaf(v, v, s); }
  for (int off = 32; off; off >>= 1) s += __shfl_xor(s, off);
  if (!lane) sq[i] = s;
}

// 32x32 tiles, 16x16 grid = 256 blocks
__global__ __launch_bounds__(256) void zz_dist(const float* __restrict__ A,
    const float* __restrict__ sq, float* __restrict__ dsum)
{
  __shared__ float Ai[32][33], Aj[32][33];
  __shared__ float red[256];
  int i0 = blockIdx.y*32, j0 = blockIdx.x*32;
  int tid = threadIdx.x, tx = tid & 15, ty = tid >> 4;
  float acc[2][2] = {};
  for (int k0 = 0; k0 < DI*DI; k0 += 32) {
    for (int t = tid; t < 32*32; t += 256) {
      int r = t >> 5, kk = t & 31, gk = k0 + kk;
      float vi = 0.f, vj = 0.f;
      if (gk < DI*DI) {
        vi = A[(size_t)(i0 + r)*(DI*DI) + gk];
        vj = A[(size_t)(j0 + r)*(DI*DI) + gk];
      }
      Ai[r][kk] = vi; Aj[r][kk] = vj;
    }
    __syncthreads();
    #pragma unroll 8
    for (int kk = 0; kk < 32; ++kk) {
      float a0 = Ai[ty*2][kk], a1 = Ai[ty*2+1][kk];
      float b0 = Aj[tx*2][kk], b1 = Aj[tx*2+1][kk];
      acc[0][0] = fmaf(a0, b0, acc[0][0]); acc[0][1] = fmaf(a0, b1, acc[0][1]);
      acc[1][0] = fmaf(a1, b0, acc[1][0]); acc[1][1] = fmaf(a1, b1, acc[1][1]);
    }
    __syncthreads();
  }
  float s = 0.f;
  #pragma unroll
  for (int u = 0; u < 2; ++u)
    #pragma unroll
    for (int v = 0; v < 2; ++v) {
      float d2 = sq[i0 + ty*2 + u] + sq[j0 + tx*2 + v] - 2.f*acc[u][v];
      d2 = fmaxf(d2, 0.f);
      s += sqrtf(d2 + 1e-12f);
    }
  red[tid] = s; __syncthreads();
  for (int st = 128; st; st >>= 1) { if (tid < st) red[tid] += red[tid + st]; __syncthreads(); }
  if (!tid) atomicAdd(dsum, red[0]);
}

__global__ void zz_dist_fin(const float* dsum, float* out)
{
  out[0] = dsum[0] * (1.f/((float)NB*(float)NB));
}

// ---------------- token GEMM via MFMA: A bf16 [M][K], BT bf16 [N][K]; OBF: bf16 output ----------------
template<int RELU, int RES, int OBF>
__global__ __launch_bounds__(256) void zz_mgemm(const short* __restrict__ A,
    const short* __restrict__ BT, const float* __restrict__ bias,
    const float* __restrict__ res, void* __restrict__ Cv, int M, int N, int K, int ntpc)
{
  int wave = threadIdx.x >> 6, lane = threadIdx.x & 63;
  int m0 = blockIdx.x*64 + wave*16;
  if (m0 >= M) return;
  int r = lane & 15, g = lane >> 4;
  int arow = m0 + r; if (arow >= M) arow = M - 1;
  const short* Ap = A + (size_t)arow*K + g*8;
  int NP = N >> 5;
  int p0 = blockIdx.y * ntpc;
  int p1 = p0 + ntpc; if (p1 > NP) p1 = NP;
  for (int ntp = p0; ntp < p1; ++ntp) {
    int n0 = ntp*32;
    const short* B0 = BT + (size_t)(n0 + r)*K + g*8;
    const short* B1 = B0 + (size_t)16*K;
    f32x4 acc0 = {0.f,0.f,0.f,0.f}, acc1 = {0.f,0.f,0.f,0.f};
    #pragma unroll 5
    for (int k0 = 0; k0 < K; k0 += 32) {
      bf16x8 af = *(const bf16x8*)(Ap + k0);
      bf16x8 b0 = *(const bf16x8*)(B0 + k0);
      bf16x8 b1 = *(const bf16x8*)(B1 + k0);
      acc0 = __builtin_amdgcn_mfma_f32_16x16x32_bf16(af, b0, acc0, 0, 0, 0);
      acc1 = __builtin_amdgcn_mfma_f32_16x16x32_bf16(af, b1, acc1, 0, 0, 0);
    }
    #pragma unroll
    for (int j = 0; j < 4; ++j) {
      int row = m0 + g*4 + j;
      if (row >= M) continue;
      int c0 = n0 + r, c1 = n0 + 16 + r;
      float v0 = acc0[j] + bias[c0];
      float v1 = acc1[j] + bias[c1];
      if (RES) { v0 += res[(size_t)row*N + c0]; v1 += res[(size_t)row*N + c1]; }
      if (RELU) { v0 = fmaxf(v0, 0.f); v1 = fmaxf(v1, 0.f); }
      if (OBF) {
        short* C = (short*)Cv;
        C[(size_t)row*N + c0] = zz_bf(v0);
        C[(size_t)row*N + c1] = zz_bf(v1);
      } else {
        float* C = (float*)Cv;
        C[(size_t)row*N + c0] = v0;
        C[(size_t)row*N + c1] = v1;
      }
    }
  }
}

// ---------------- f32 tiled GEMM (head) ----------------
template<int RELU, int RES>
__global__ __launch_bounds__(256) void zz_gemm(const float* __restrict__ A,
    const float* __restrict__ Bw, const float* __restrict__ bias,
    const float* __restrict__ res, float* __restrict__ C, int M, int N, int K)
{
  __shared__ float As[64][33];
  __shared__ float Bs[32][136];
  int m0 = blockIdx.y*64, n0 = blockIdx.x*128;
  int tid = threadIdx.x, tx = tid & 15, ty = tid >> 4;
  float acc[4][8] = {};
  for (int k0 = 0; k0 < K; k0 += 32) {
    for (int i = tid; i < 64*32; i += 256) {
      int rr = i >> 5, kk = i & 31;
      int gm = m0 + rr, gk = k0 + kk;
      As[rr][kk] = (gm < M && gk < K) ? A[(size_t)gm*K + gk] : 0.f;
    }
    for (int i = tid; i < 32*128; i += 256) {
      int kk = i >> 7, n = i & 127;
      int gk = k0 + kk, gn = n0 + n;
      Bs[kk][n] = (gk < K && gn < N) ? Bw[(size_t)gk*N + gn] : 0.f;
    }
    __syncthreads();
    #pragma unroll 4
    for (int kk = 0; kk < 32; ++kk) {
      float a[4];
      #pragma unroll
      for (int u = 0; u < 4; ++u) a[u] = As[ty*4 + u][kk];
      float4 b0 = *(const float4*)&Bs[kk][tx*8];
      float4 b1 = *(const float4*)&Bs[kk][tx*8 + 4];
      float b[8] = {b0.x,b0.y,b0.z,b0.w,b1.x,b1.y,b1.z,b1.w};
      #pragma unroll
      for (int u = 0; u < 4; ++u)
        #pragma unroll
        for (int v = 0; v < 8; ++v) acc[u][v] = fmaf(a[u], b[v], acc[u][v]);
    }
    __syncthreads();
  }
  #pragma unroll
  for (int u = 0; u < 4; ++u) {
    int gm = m0 + ty*4 + u;
    if (gm >= M) continue;
    #pragma unroll
    for (int v = 0; v < 8; ++v) {
      int gn = n0 + tx*8 + v;
      if (gn >= N) continue;
      float val = acc[u][v] + bias[gn];
      if (RES) val += res[(size_t)gm*N + gn];
      if (RELU) val = fmaxf(val, 0.f);
      C[(size_t)gm*N + gn] = val;
    }
  }
}

// ---------------- fused MFMA attention v3: QKV bf16 (Q pre-scaled), O bf16 ----------------
__global__ __launch_bounds__(256) void zz_fattn(const short* __restrict__ QKV,
    const int* __restrict__ lengths, short* __restrict__ O, int b0, int CB)
{
  __shared__ short K_lds[224][66];
  __shared__ short VT[48][TP];
  __shared__ short PT[4][16][TP];
  const float LOG2E = 1.44269504088896f;
  int bh = blockIdx.x, bl = bh >> 2, h = bh & 3;
  int tid = threadIdx.x, wave = tid >> 6, lane = tid & 63;
  int len = lengths[b0 + bl];

  for (int i = tid; i < 224*64; i += 256) {
    int t = i >> 6, d = i & 63;
    short kv = 0, vv = 0;
    if (t < S_LEN && d < DH) {
      const short* base = QKV + ((size_t)t*CB + bl)*(3*DT) + DT + h*DH + d;
      kv = base[0];        // K
      vv = base[DT];       // V
    }
    K_lds[t][d] = kv;
    if (d < 48) VT[d][t] = vv;
  }
  __syncthreads();

  int r = lane & 15, g = lane >> 4;
  for (int mt = wave; mt < 14; mt += 4) {
    int m0 = mt*16;
    int qrow = m0 + r; if (qrow > S_LEN-1) qrow = S_LEN-1;
    const short* qp = QKV + ((size_t)qrow*CB + bl)*(3*DT) + h*DH;
    bf16x8 qf0 = *(const bf16x8*)(qp + g*8);
    bf16x8 qf1 = (g == 0) ? *(const bf16x8*)(qp + 32) : (bf16x8){0,0,0,0,0,0,0,0};
    f32x4 acc[14];
    #pragma unroll
    for (int nt = 0; nt < 14; ++nt) acc[nt] = (f32x4){0.f,0.f,0.f,0.f};
    #pragma unroll
    for (int nt = 0; nt < 14; ++nt) {
      int trow = nt*16 + r; if (trow > S_LEN-1) trow = S_LEN-1;
      bf16x8 b0 = *(const bf16x8*)&K_lds[trow][g*8];
      bf16x8 b1 = *(const bf16x8*)&K_lds[trow][32 + g*8];
      acc[nt] = __builtin_amdgcn_mfma_f32_16x16x32_bf16(qf0, b0, acc[nt], 0, 0, 0);
      acc[nt] = __builtin_amdgcn_mfma_f32_16x16x32_bf16(qf1, b1, acc[nt], 0, 0, 0);
    }
    #pragma unroll
    for (int j = 0; j < 4; ++j) {
      float mx = -3e38f;
      #pragma unroll
      for (int nt = 0; nt < 14; ++nt) {
        int t = nt*16 + r;
        float v = (t < len) ? acc[nt][j] : -1e9f;
        acc[nt][j] = v;
        mx = fmaxf(mx, v);
      }
      mx = fmaxf(mx, __shfl_xor(mx, 1));
      mx = fmaxf(mx, __shfl_xor(mx, 2));
      mx = fmaxf(mx, __shfl_xor(mx, 4));
      mx = fmaxf(mx, __shfl_xor(mx, 8));
      float sum = 0.f;
      #pragma unroll
      for (int nt = 0; nt < 14; ++nt) {
        float p = exp2f((acc[nt][j] - mx) * LOG2E);
        acc[nt][j] = p;
        sum += p;
      }
      sum += __shfl_xor(sum, 1);
      sum += __shfl_xor(sum, 2);
      sum += __shfl_xor(sum, 4);
      sum += __shfl_xor(sum, 8);
      float inv = 1.f / sum;
      #pragma unroll
      for (int nt = 0; nt < 14; ++nt)
        PT[wave][g*4 + j][nt*16 + r] = zz_bf(acc[nt][j] * inv);
    }
    f32x4 oacc0 = {0.f,0.f,0.f,0.f}, oacc1 = {0.f,0.f,0.f,0.f}, oacc2 = {0.f,0.f,0.f,0.f};
    #pragma unroll
    for (int ks = 0; ks < 7; ++ks) {
      bf16x8 pa = *(const bf16x8*)&PT[wave][r][ks*32 + g*8];
      bf16x8 v0 = *(const bf16x8*)&VT[r][ks*32 + g*8];
      bf16x8 v1 = *(const bf16x8*)&VT[16 + r][ks*32 + g*8];
      bf16x8 v2 = *(const bf16x8*)&VT[32 + r][ks*32 + g*8];
      oacc0 = __builtin_amdgcn_mfma_f32_16x16x32_bf16(pa, v0, oacc0, 0, 0, 0);
      oacc1 = __builtin_amdgcn_mfma_f32_16x16x32_bf16(pa, v1, oacc1, 0, 0, 0);
      oacc2 = __builtin_amdgcn_mfma_f32_16x16x32_bf16(pa, v2, oacc2, 0, 0, 0);
    }
    #pragma unroll
    for (int j = 0; j < 4; ++j) {
      int row = m0 + g*4 + j;
      if (row >= S_LEN) continue;
      short* op = O + ((size_t)row*CB + bl)*DT + h*DH;
      op[r] = zz_bf(oacc0[j]);
      op[16 + r] = zz_bf(oacc1[j]);
      if (32 + r < DH) op[32 + r] = zz_bf(oacc2[j]);
    }
  }
}

// ---------------- layernorm (dual write f32 + bf16) ----------------
__global__ __launch_bounds__(256) void zz_ln(const float* __restrict__ X,
    const float* __restrict__ g, const float* __restrict__ bt,
    float* __restrict__ Y, short* __restrict__ Yb, int ntok)
{
  int tok = blockIdx.x*4 + (threadIdx.x >> 6);
  if (tok >= ntok) return;
  int lane = threadIdx.x & 63;
  const float* x = X + (size_t)tok*DT;
  float v0 = x[lane], v1 = x[lane + 64];
  float v2 = (lane < 32) ? x[lane + 128] : 0.f;
  float s = v0 + v1 + v2;
  for (int off = 32; off; off >>= 1) s += __shfl_xor(s, off);
  float mean = s * (1.f/160.f);
  float d0 = v0 - mean, d1 = v1 - mean, d2 = (lane < 32) ? (v2 - mean) : 0.f;
  float q = d0*d0 + d1*d1 + d2*d2;
  for (int off = 32; off; off >>= 1) q += __shfl_xor(q, off);
  float inv = 1.f / sqrtf(q * (1.f/160.f) + 1e-5f);
  float* y = Y + (size_t)tok*DT;
  short* yb = Yb + (size_t)tok*DT;
  float o0 = d0*inv*g[lane]      + bt[lane];
  float o1 = d1*inv*g[lane + 64] + bt[lane + 64];
  y[lane]      = o0; yb[lane]      = zz_bf(o0);
  y[lane + 64] = o1; yb[lane + 64] = zz_bf(o1);
  if (lane < 32) {
    float o2 = d2*inv*g[lane + 128] + bt[lane + 128];
    y[lane + 128] = o2; yb[lane + 128] = zz_bf(o2);
  }
}

// ---------------- masked mean + feat concat ----------------
__global__ __launch_bounds__(256) void zz_agg(const float* __restrict__ XCH,
    const int* __restrict__ lengths, const float* __restrict__ emb, float* __restrict__ feat,
    int b0, int CB)
{
  int bl = blockIdx.x, tid = threadIdx.x;
  int b = b0 + bl;
  int len = lengths[b];
  if (tid < DT) {
    float acc = 0.f;
    for (int s = 0; s < len; ++s) acc += XCH[((size_t)s*CB + bl)*DT + tid];
    feat[(size_t)b*DFIN + tid] = acc / (float)(len + 1);
  } else if (tid < DFIN) {
    feat[(size_t)b*DFIN + tid] = emb[b*DI + (tid - DT)];
  }
}

// ======================================================================
extern "C" void kernel_launch(void* const* d_in, const int* in_sizes, int n_in,
                              void* d_out, int out_size, void* d_ws, size_t ws_size,
                              hipStream_t stream)
{
  (void)in_sizes; (void)n_in; (void)out_size;
  const float* src     = (const float*)d_in[0];
  const float* statc   = (const float*)d_in[1];
  const float* times   = (const float*)d_in[2];
  const int*   lengths = (const int*)  d_in[3];
  const float* R_u     = (const float*)d_in[4];
  const float* emb_w   = (const float*)d_in[5];
  const float* emb_b   = (const float*)d_in[6];
  const float* W1      = (const float*)d_in[7];
  const float* a1_s    = (const float*)d_in[8];
  const float* a1_d    = (const float*)d_in[9];
  const float* W2      = (const float*)d_in[10];
  const float* a2_s    = (const float*)d_in[11];
  const float* a2_d    = (const float*)d_in[12];
  const float* attn_in_w  = (const float*)d_in[13];
  const float* attn_in_b  = (const float*)d_in[14];
  const float* attn_out_w = (const float*)d_in[15];
  const float* attn_out_b = (const float*)d_in[16];
  const float* ff1_w = (const float*)d_in[17];
  const float* ff1_b = (const float*)d_in[18];
  const float* ff2_w = (const float*)d_in[19];
  const float* ff2_b = (const float*)d_in[20];
  const float* ln1_g = (const float*)d_in[21];
  const float* ln1_b = (const float*)d_in[22];
  const float* ln2_g = (const float*)d_in[23];
  const float* ln2_b = (const float*)d_in[24];
  const float* mlp1_w = (const float*)d_in[25];
  const float* mlp1_b = (const float*)d_in[26];
  const float* mlp2_w = (const float*)d_in[27];
  const float* mlp2_b = (const float*)d_in[28];

  // ---- small persistent buffers (floats) ----
  float* ws = (float*)d_ws;
  float* A1    = ws;                 // 663,552
  float* A2    = ws + 663552;        // 663,552
  float* SS    = ws + 1327104;       // 18,432
  float* SD    = ws + 1345536;       // 18,432
  float* SQB   = ws + 1363968;       // 512
  float* DSUM  = ws + 1364480;       // 64
  float* EMB   = ws + 1364544;       // 18,432
  float* FEAT  = ws + 1382976;       // 100,352
  float* FFEAT = ws + 1483328;       // 100,352
  float* ZEROB = ws + 1583680;       // 896 (zeroed bias)
  float* BQ    = ws + 1584576;       // 960 (scaled qkv bias)
  // bf16 weight area (shorts), 16B-aligned
  short* wb = (short*)(ws + 1585536);
  short* W1T   = wb;                 // 746,496
  short* W2T   = wb + 746496;        // 746,496
  short* WTqkv = wb + 1492992;       // 153,600
  short* WTao  = wb + 1646592;       // 51,200
  short* WTf1  = wb + 1697792;       // 40,960
  short* WTf2  = wb + 1738752;       // 40,960
  const size_t CHBASE = 1585536 + 889856;   // = 2,475,392 floats
  float* CH = ws + CHBASE;

  // ---- pick largest chunk size that fits ws_size ----
  // chunk floats: XCH 34400 + XCHbf 17200 + max(GAT 62208, TRANSF 116960) = 168,560 per CB
  int CB = 8;
  const int cands[7] = {512, 256, 128, 64, 32, 16, 8};
  for (int c = 0; c < 7; ++c) {
    size_t need = 4ull * (CHBASE + 168560ull * (size_t)cands[c]);
    if (need <= ws_size) { CB = cands[c]; break; }
  }
  const int NCH = NB / CB;
  const int NTOKC = S_LEN * CB;

  float* XCH   = CH;                               // 34,400*CB f32
  short* XCHb  = (short*)(CH + (size_t)34400*CB);  // 17,200*CB f-eq
  float* R0    = CH + (size_t)51600*CB;
  // GAT view
  short* Xbf   = (short*)R0;                       // 15,552*CB f-eq
  float* XPc   = R0 + (size_t)15552*CB;            // 31,104*CB f32
  short* H1bf  = (short*)(R0 + (size_t)46656*CB);  // 15,552*CB f-eq
  // transformer view (GAT bufs dead)
  short* QKVb  = (short*)R0;                       // 51,600*CB f-eq
  short* OAb   = (short*)(R0 + (size_t)51600*CB);  // 17,200*CB f-eq
  float* Tc    = R0 + (size_t)68800*CB;            // 34,400*CB f32
  short* Ybf   = (short*)(R0 + (size_t)103200*CB); // 13,760*CB f-eq

  hipMemsetAsync(DSUM, 0, 4, stream);
  hipMemsetAsync(ZEROB, 0, 896*4, stream);
  zz_emb<<<dim3(CDIV(NB*DI,256)), 256, 0, stream>>>(statc, emb_w, emb_b, EMB);
  zz_biasq<<<dim3(4), 256, 0, stream>>>(attn_in_b, BQ);

  // ---- one-time weight transpose+bf16 conversions ----
  zz_wcvt<<<dim3(CDIV(FINP*FINP,256)), 256, 0, stream>>>(W1, W1T, FIN, FIN, FINP, FINP, 0, 1.f);
  zz_wcvt<<<dim3(CDIV(FINP*FINP,256)), 256, 0, stream>>>(W2, W2T, FIN, FIN, FINP, FINP, 0, 1.f);
  for (int l = 0; l < 2; ++l) {
    zz_wcvt<<<dim3(CDIV(480*160,256)), 256, 0, stream>>>(attn_in_w + (size_t)l*DT*3*DT,
        WTqkv + (size_t)l*76800, DT, 3*DT, DT, 3*DT, DT, 0.15811388300841897f);
    zz_wcvt<<<dim3(CDIV(160*160,256)), 256, 0, stream>>>(attn_out_w + (size_t)l*DT*DT,
        WTao + (size_t)l*25600, DT, DT, DT, DT, 0, 1.f);
    zz_wcvt<<<dim3(CDIV(128*160,256)), 256, 0, stream>>>(ff1_w + (size_t)l*DT*NHID,
        WTf1 + (size_t)l*20480, DT, NHID, DT, NHID, 0, 1.f);
    zz_wcvt<<<dim3(CDIV(160*128,256)), 256, 0, stream>>>(ff2_w + (size_t)l*NHID*DT,
        WTf2 + (size_t)l*20480, NHID, DT, NHID, DT, 0, 1.f);
  }

  for (int ch = 0; ch < NCH; ++ch) {
    int b0 = ch * CB;
    // ---- GAT stack (chunk) ----
    zz_build_x<<<dim3(CDIV(CB*DI*S_LEN,256)), 256, 0, stream>>>(src, R_u, Xbf, b0, CB);
    zz_zeropad_bf<<<dim3(CDIV(CB*DI,256)), 256, 0, stream>>>(Xbf, CB);
    zz_mgemm<0,0,0><<<dim3(CDIV(CB*DI,64), 7), 256, 0, stream>>>(Xbf, W1T, ZEROB, nullptr,
        XPc, CB*DI, FINP, FINP, 4);
    zz_gat_attvec<<<dim3(DI, CB), 64, 0, stream>>>(XPc, a1_s, a1_d, SS, SD, b0);
    zz_gat_alpha<<<dim3(CB), 256, 0, stream>>>(SS, SD, (const float*)nullptr, A1, b0);
    zz_gat_apply<<<dim3(4, CB), 256, 0, stream>>>(A1, XPc, nullptr, H1bf, 0, b0, CB);
    zz_zeropad_bf<<<dim3(CDIV(CB*DI,256)), 256, 0, stream>>>(H1bf, CB);
    zz_mgemm<0,0,0><<<dim3(CDIV(CB*DI,64), 7), 256, 0, stream>>>(H1bf, W2T, ZEROB, nullptr,
        XPc, CB*DI, FINP, FINP, 4);
    zz_gat_attvec<<<dim3(DI, CB), 64, 0, stream>>>(XPc, a2_s, a2_d, SS, SD, b0);
    zz_gat_alpha<<<dim3(CB), 256, 0, stream>>>(SS, SD, A1, A2, b0);
    zz_gat_apply<<<dim3(4, CB), 256, 0, stream>>>(A2, XPc, XCH, XCHb, 1, b0, CB);
    zz_pe<<<dim3(CDIV(CB*S_LEN*16,256)), 256, 0, stream>>>(times, XCH, XCHb, b0, CB);

    // ---- transformer (chunk) ----
    for (int l = 0; l < 2; ++l) {
      zz_mgemm<0,0,1><<<dim3(CDIV(NTOKC,64), 1), 256, 0, stream>>>(XCHb,
          WTqkv + (size_t)l*76800, BQ + l*480, nullptr, QKVb, NTOKC, 3*DT, DT, 15);
      zz_fattn<<<dim3(CB*NH), 256, 0, stream>>>(QKVb, lengths, OAb, b0, CB);
      zz_mgemm<0,1,0><<<dim3(CDIV(NTOKC,64), 1), 256, 0, stream>>>(OAb,
          WTao + (size_t)l*25600, attn_out_b + l*DT, XCH, Tc, NTOKC, DT, DT, 5);
      zz_ln<<<dim3(CDIV(NTOKC,4)), 256, 0, stream>>>(Tc, ln1_g + l*DT, ln1_b + l*DT, XCH, XCHb, NTOKC);
      zz_mgemm<1,0,1><<<dim3(CDIV(NTOKC,64), 1), 256, 0, stream>>>(XCHb,
          WTf1 + (size_t)l*20480, ff1_b + l*NHID, nullptr, Ybf, NTOKC, NHID, DT, 4);
      zz_mgemm<0,1,0><<<dim3(CDIV(NTOKC,64), 1), 256, 0, stream>>>(Ybf,
          WTf2 + (size_t)l*20480, ff2_b + l*DT, XCH, Tc, NTOKC, DT, NHID, 5);
      zz_ln<<<dim3(CDIV(NTOKC,4)), 256, 0, stream>>>(Tc, ln2_g + l*DT, ln2_b + l*DT, XCH, XCHb, NTOKC);
    }

    zz_agg<<<dim3(CB), 256, 0, stream>>>(XCH, lengths, EMB, FEAT, b0, CB);
  }

  // ---- distance from alpha2 (full batch) ----
  zz_sq<<<dim3(NB), 64, 0, stream>>>(A2, SQB);
  zz_dist<<<dim3(16, 16), 256, 0, stream>>>(A2, SQB, DSUM);
  zz_dist_fin<<<1, 1, 0, stream>>>(DSUM, (float*)d_out + 1024);

  // ---- head (f32, tiny) ----
  zz_gemm<1,0><<<dim3(CDIV(DFIN,128), CDIV(NB,64)), 256, 0, stream>>>(FEAT, mlp1_w, mlp1_b,
      nullptr, FFEAT, NB, DFIN, DFIN);
  zz_gemm<0,0><<<dim3(1, CDIV(NB,64)), 256, 0, stream>>>(FFEAT, mlp2_w, mlp2_b,
      nullptr, (float*)d_out, NB, 2, DFIN);
}

// Round 14
// 2190.237 us; speedup vs baseline: 1.8202x; 1.0422x over previous
//
#include <hip/hip_runtime.h>
#include <hip/hip_bf16.h>
#include <math.h>

#define S_LEN 215
#define NB    512
#define DI    36
#define DMODEL 144
#define DT    160
#define NH    4
#define DH    40
#define NHID  128
#define FIN   860
#define FINP  864
#define DFIN  196
#define TP    226
#define CDIV(a,b) (((a)+(b)-1)/(b))

typedef __attribute__((ext_vector_type(8))) short bf16x8;
typedef __attribute__((ext_vector_type(4))) float f32x4;

__device__ inline short zz_bf(float v) {
  union { __hip_bfloat16 h; short s; } c; c.h = __float2bfloat16(v); return c.s;
}

// ---------------- weight transpose + bf16 convert: WT[n][k] = bf16(W[k][n] * (n<qcols?qs:1)) ----------------
__global__ __launch_bounds__(256) void zz_wcvt(const float* __restrict__ W,
    short* __restrict__ WT, int K, int N, int Kpad, int Npad, int qcols, float qs)
{
  int idx = blockIdx.x*256 + threadIdx.x;
  if (idx >= Npad*Kpad) return;
  int n = idx / Kpad, k = idx % Kpad;
  float v = (n < N && k < K) ? W[(size_t)k*N + n] : 0.f;
  if (n < qcols) v *= qs;
  WT[idx] = zz_bf(v);
}

// ---------------- scaled qkv bias ----------------
__global__ __launch_bounds__(256) void zz_biasq(const float* __restrict__ b, float* __restrict__ out)
{
  int i = blockIdx.x*256 + threadIdx.x;
  if (i >= 960) return;
  int c = i % 480;
  out[i] = b[i] * ((c < DT) ? 0.15811388300841897f : 1.f);
}

// ---------------- build x chunk -> bf16 [CB*36][864] ----------------
__global__ __launch_bounds__(256) void zz_build_x(const float* __restrict__ src,
    const float* __restrict__ R_u, short* __restrict__ X, int b0, int CB)
{
  int idx = blockIdx.x*256 + threadIdx.x;           // (bl,i,s)
  if (idx >= CB*DI*S_LEN) return;
  int s = idx % S_LEN; int t = idx / S_LEN; int i = t % DI; int bl = t / DI;
  float v = src[((size_t)s*NB + b0 + bl)*(2*DI) + i];
  float4 r = *(const float4*)(R_u + i*4);
  short4 o;
  o.x = zz_bf(fmaxf(v*r.x, 0.f)); o.y = zz_bf(fmaxf(v*r.y, 0.f));
  o.z = zz_bf(fmaxf(v*r.z, 0.f)); o.w = zz_bf(fmaxf(v*r.w, 0.f));
  *(short4*)(X + (size_t)(bl*DI + i)*FINP + s*4) = o;
}

// ---------------- zero pad cols 860..863 of bf16 buffer ----------------
__global__ __launch_bounds__(256) void zz_zeropad_bf(short* __restrict__ buf, int CB)
{
  int idx = blockIdx.x*256 + threadIdx.x;
  if (idx >= CB*DI) return;
  short4 z = {0,0,0,0};
  *(short4*)(buf + (size_t)idx*FINP + FIN) = z;
}

// ---------------- positional encoding (dual write f32 + bf16) ----------------
__global__ __launch_bounds__(256) void zz_pe(const float* __restrict__ times,
    float* __restrict__ XCH, short* __restrict__ XCHb, int b0, int CB)
{
  int idx = blockIdx.x*256 + threadIdx.x;           // (tl, k)
  if (idx >= CB*S_LEN*16) return;
  int k = idx & 15; int tl = idx >> 4;
  int bl = tl % CB; int s = tl / CB;
  int j = k & 7;
  float ts = powf(215.f, (float)j * (1.f/7.f)) * 100.f;
  float sc = times[(size_t)s*NB + b0 + bl] / ts;
  float v = (k < 8) ? sinf(sc) : cosf(sc);
  XCH[(size_t)tl*DT + DMODEL + k] = v;
  XCHb[(size_t)tl*DT + DMODEL + k] = zz_bf(v);
}

// ---------------- emb ----------------
__global__ __launch_bounds__(256) void zz_emb(const float* __restrict__ st,
    const float* __restrict__ w, const float* __restrict__ bias, float* __restrict__ emb)
{
  int idx = blockIdx.x*256 + threadIdx.x;
  if (idx >= NB*DI) return;
  int b = idx / DI, k = idx % DI;
  float acc = bias[k];
  #pragma unroll
  for (int j = 0; j < 9; ++j) acc = fmaf(st[b*9 + j], w[j*DI + k], acc);
  emb[idx] = acc;
}

// ---------------- per-row dots (XP f32 stride FINP) ----------------
__global__ __launch_bounds__(64) void zz_gat_attvec(const float* __restrict__ XP,
    const float* __restrict__ a_s, const float* __restrict__ a_d,
    float* __restrict__ ss, float* __restrict__ sd, int b0)
{
  int i = blockIdx.x, bl = blockIdx.y, lane = threadIdx.x;
  const float* row = XP + ((size_t)bl*DI + i)*FINP;
  float ps = 0.f, pd = 0.f;
  for (int k = lane; k < FIN; k += 64) {
    float v = row[k];
    ps = fmaf(v, a_s[k], ps);
    pd = fmaf(v, a_d[k], pd);
  }
  for (int off = 32; off; off >>= 1) { ps += __shfl_xor(ps, off); pd += __shfl_xor(pd, off); }
  if (!lane) { ss[(b0 + bl)*DI + i] = ps; sd[(b0 + bl)*DI + i] = pd; }
}

// ---------------- alpha softmax ----------------
__global__ __launch_bounds__(256) void zz_gat_alpha(const float* __restrict__ ss,
    const float* __restrict__ sd, const float* __restrict__ edge, float* __restrict__ alpha, int b0)
{
  int b = b0 + blockIdx.x;
  int wv = threadIdx.x >> 6, lane = threadIdx.x & 63;
  for (int i = wv; i < DI; i += 4) {
    float di = sd[b*DI + i];
    float e = -3e38f, x = 0.f;
    if (lane < DI) {
      x = di + ss[b*DI + lane];
      x = (x >= 0.f) ? x : 0.2f*x;
      e = x;
    }
    float m = e;
    for (int off = 32; off; off >>= 1) m = fmaxf(m, __shfl_xor(m, off));
    float p = (lane < DI) ? expf(e - m) : 0.f;
    float s = p;
    for (int off = 32; off; off >>= 1) s += __shfl_xor(s, off);
    if (lane < DI) {
      float a = p / s;
      size_t o = ((size_t)b*DI + i)*DI + lane;
      if (edge) a *= edge[o];
      alpha[o] = a;
    }
  }
}

// ---------------- gat apply: mode0 -> bf16 H1 ; mode1 -> XCH f32 + bf16 ----------------
__global__ __launch_bounds__(256) void zz_gat_apply(const float* __restrict__ alpha,
    const float* __restrict__ XP, float* __restrict__ outf, short* __restrict__ outb,
    int mode, int b0, int CB)
{
  __shared__ float Al[DI][37];
  __shared__ float Xs[DI][260];
  int bl = blockIdx.y, n0 = blockIdx.x * 256;
  int tid = threadIdx.x;
  int nt = tid & 63, mg = tid >> 6;
  const float* ab = alpha + ((size_t)(b0 + bl))*DI*DI;
  for (int i = tid; i < DI*DI; i += 256) Al[i/DI][i%DI] = ab[i];
  const float* XPb = XP + (size_t)bl*DI*FINP;
  for (int i = tid; i < DI*256; i += 256) {
    int k = i >> 8, nn = i & 255, gn = n0 + nn;
    Xs[k][nn] = (gn < FIN) ? XPb[(size_t)k*FINP + gn] : 0.f;
  }
  __syncthreads();
  float acc[9][4] = {};
  #pragma unroll 4
  for (int k = 0; k < DI; ++k) {
    float4 x4 = *(const float4*)&Xs[k][nt*4];
    float xb[4] = {x4.x, x4.y, x4.z, x4.w};
    #pragma unroll
    for (int m = 0; m < 9; ++m) {
      float av = Al[mg*9 + m][k];
      #pragma unroll
      for (int v = 0; v < 4; ++v) acc[m][v] = fmaf(av, xb[v], acc[m][v]);
    }
  }
  int gn = n0 + nt*4;
  if (gn < FIN) {
    if (mode == 0) {
      short* ob = outb + (size_t)bl*DI*FINP;
      #pragma unroll
      for (int m = 0; m < 9; ++m) {
        short4 o4 = {zz_bf(acc[m][0]), zz_bf(acc[m][1]), zz_bf(acc[m][2]), zz_bf(acc[m][3])};
        *(short4*)(ob + (size_t)(mg*9 + m)*FINP + gn) = o4;
      }
    } else {
      int s = gn >> 2;
      float* op  = outf + ((size_t)s*CB + bl)*DT;
      short* opb = outb + ((size_t)s*CB + bl)*DT;
      #pragma unroll
      for (int m = 0; m < 9; ++m) {
        float4 o4 = {acc[m][0], acc[m][1], acc[m][2], acc[m][3]};
        *(float4*)(op + (mg*9 + m)*4) = o4;
        short4 s4 = {zz_bf(acc[m][0]), zz_bf(acc[m][1]), zz_bf(acc[m][2]), zz_bf(acc[m][3])};
        *(short4*)(opb + (mg*9 + m)*4) = s4;
      }
    }
  }
}

// ---------------- distance helpers ----------------
__global__ __launch_bounds__(64) void zz_sq(const float* __restrict__ A, float* __restrict__ sq)
{
  int i = blockIdx.x, lane = threadIdx.x;
  const float* row = A + (size_t)i*(DI*DI);
  float s = 0.f;
  for (int k = lane; k < DI*DI; k += 64) { float v = row[k]; s = fmaf(v, v, s); }
  for (int off = 32; off; off >>= 1) s += __shfl_xor(s, off);
  if (!lane) sq[i] = s;
}

__global__ __launch_bounds__(256) void zz_dist(const float* __restrict__ A,
    const float* __restrict__ sq, float* __restrict__ dsum)
{
  __shared__ float Ai[32][33], Aj[32][33];
  __shared__ float red[256];
  int i0 = blockIdx.y*32, j0 = blockIdx.x*32;
  int tid = threadIdx.x, tx = tid & 15, ty = tid >> 4;
  float acc[2][2] = {};
  for (int k0 = 0; k0 < DI*DI; k0 += 32) {
    for (int t = tid; t < 32*32; t += 256) {
      int r = t >> 5, kk = t & 31, gk = k0 + kk;
      float vi = 0.f, vj = 0.f;
      if (gk < DI*DI) {
        vi = A[(size_t)(i0 + r)*(DI*DI) + gk];
        vj = A[(size_t)(j0 + r)*(DI*DI) + gk];
      }
      Ai[r][kk] = vi; Aj[r][kk] = vj;
    }
    __syncthreads();
    #pragma unroll 8
    for (int kk = 0; kk < 32; ++kk) {
      float a0 = Ai[ty*2][kk], a1 = Ai[ty*2+1][kk];
      float b0 = Aj[tx*2][kk], b1 = Aj[tx*2+1][kk];
      acc[0][0] = fmaf(a0, b0, acc[0][0]); acc[0][1] = fmaf(a0, b1, acc[0][1]);
      acc[1][0] = fmaf(a1, b0, acc[1][0]); acc[1][1] = fmaf(a1, b1, acc[1][1]);
    }
    __syncthreads();
  }
  float s = 0.f;
  #pragma unroll
  for (int u = 0; u < 2; ++u)
    #pragma unroll
    for (int v = 0; v < 2; ++v) {
      float d2 = sq[i0 + ty*2 + u] + sq[j0 + tx*2 + v] - 2.f*acc[u][v];
      d2 = fmaxf(d2, 0.f);
      s += sqrtf(d2 + 1e-12f);
    }
  red[tid] = s; __syncthreads();
  for (int st = 128; st; st >>= 1) { if (tid < st) red[tid] += red[tid + st]; __syncthreads(); }
  if (!tid) atomicAdd(dsum, red[0]);
}

__global__ void zz_dist_fin(const float* dsum, float* out)
{
  out[0] = dsum[0] * (1.f/((float)NB*(float)NB));
}

// ---------------- token GEMM via MFMA: A bf16 [M][K], BT bf16 [N][K]; OBF: bf16 output ----------------
template<int RELU, int RES, int OBF>
__global__ __launch_bounds__(256) void zz_mgemm(const short* __restrict__ A,
    const short* __restrict__ BT, const float* __restrict__ bias,
    const float* __restrict__ res, void* __restrict__ Cv, int M, int N, int K, int ntpc)
{
  int wave = threadIdx.x >> 6, lane = threadIdx.x & 63;
  int m0 = blockIdx.x*64 + wave*16;
  if (m0 >= M) return;
  int r = lane & 15, g = lane >> 4;
  int arow = m0 + r; if (arow >= M) arow = M - 1;
  const short* Ap = A + (size_t)arow*K + g*8;
  int NP = N >> 5;
  int p0 = blockIdx.y * ntpc;
  int p1 = p0 + ntpc; if (p1 > NP) p1 = NP;
  for (int ntp = p0; ntp < p1; ++ntp) {
    int n0 = ntp*32;
    const short* B0 = BT + (size_t)(n0 + r)*K + g*8;
    const short* B1 = B0 + (size_t)16*K;
    f32x4 acc0 = {0.f,0.f,0.f,0.f}, acc1 = {0.f,0.f,0.f,0.f};
    #pragma unroll 5
    for (int k0 = 0; k0 < K; k0 += 32) {
      bf16x8 af = *(const bf16x8*)(Ap + k0);
      bf16x8 b0 = *(const bf16x8*)(B0 + k0);
      bf16x8 b1 = *(const bf16x8*)(B1 + k0);
      acc0 = __builtin_amdgcn_mfma_f32_16x16x32_bf16(af, b0, acc0, 0, 0, 0);
      acc1 = __builtin_amdgcn_mfma_f32_16x16x32_bf16(af, b1, acc1, 0, 0, 0);
    }
    #pragma unroll
    for (int j = 0; j < 4; ++j) {
      int row = m0 + g*4 + j;
      if (row >= M) continue;
      int c0 = n0 + r, c1 = n0 + 16 + r;
      float v0 = acc0[j] + bias[c0];
      float v1 = acc1[j] + bias[c1];
      if (RES) { v0 += res[(size_t)row*N + c0]; v1 += res[(size_t)row*N + c1]; }
      if (RELU) { v0 = fmaxf(v0, 0.f); v1 = fmaxf(v1, 0.f); }
      if (OBF) {
        short* C = (short*)Cv;
        C[(size_t)row*N + c0] = zz_bf(v0);
        C[(size_t)row*N + c1] = zz_bf(v1);
      } else {
        float* C = (float*)Cv;
        C[(size_t)row*N + c0] = v0;
        C[(size_t)row*N + c1] = v1;
      }
    }
  }
}

// ---------------- f32 tiled GEMM (head) ----------------
template<int RELU, int RES>
__global__ __launch_bounds__(256) void zz_gemm(const float* __restrict__ A,
    const float* __restrict__ Bw, const float* __restrict__ bias,
    const float* __restrict__ res, float* __restrict__ C, int M, int N, int K)
{
  __shared__ float As[64][33];
  __shared__ float Bs[32][136];
  int m0 = blockIdx.y*64, n0 = blockIdx.x*128;
  int tid = threadIdx.x, tx = tid & 15, ty = tid >> 4;
  float acc[4][8] = {};
  for (int k0 = 0; k0 < K; k0 += 32) {
    for (int i = tid; i < 64*32; i += 256) {
      int rr = i >> 5, kk = i & 31;
      int gm = m0 + rr, gk = k0 + kk;
      As[rr][kk] = (gm < M && gk < K) ? A[(size_t)gm*K + gk] : 0.f;
    }
    for (int i = tid; i < 32*128; i += 256) {
      int kk = i >> 7, n = i & 127;
      int gk = k0 + kk, gn = n0 + n;
      Bs[kk][n] = (gk < K && gn < N) ? Bw[(size_t)gk*N + gn] : 0.f;
    }
    __syncthreads();
    #pragma unroll 4
    for (int kk = 0; kk < 32; ++kk) {
      float a[4];
      #pragma unroll
      for (int u = 0; u < 4; ++u) a[u] = As[ty*4 + u][kk];
      float4 b0 = *(const float4*)&Bs[kk][tx*8];
      float4 b1 = *(const float4*)&Bs[kk][tx*8 + 4];
      float b[8] = {b0.x,b0.y,b0.z,b0.w,b1.x,b1.y,b1.z,b1.w};
      #pragma unroll
      for (int u = 0; u < 4; ++u)
        #pragma unroll
        for (int v = 0; v < 8; ++v) acc[u][v] = fmaf(a[u], b[v], acc[u][v]);
    }
    __syncthreads();
  }
  #pragma unroll
  for (int u = 0; u < 4; ++u) {
    int gm = m0 + ty*4 + u;
    if (gm >= M) continue;
    #pragma unroll
    for (int v = 0; v < 8; ++v) {
      int gn = n0 + tx*8 + v;
      if (gn >= N) continue;
      float val = acc[u][v] + bias[gn];
      if (RES) val += res[(size_t)gm*N + gn];
      if (RELU) val = fmaxf(val, 0.f);
      C[(size_t)gm*N + gn] = val;
    }
  }
}

// ---------------- fused MFMA attention v3: QKV bf16 (Q pre-scaled), O bf16 ----------------
__global__ __launch_bounds__(256) void zz_fattn(const short* __restrict__ QKV,
    const int* __restrict__ lengths, short* __restrict__ O, int b0, int CB)
{
  __shared__ short K_lds[224][66];
  __shared__ short VT[48][TP];
  __shared__ short PT[4][16][TP];
  const float LOG2E = 1.44269504088896f;
  int bh = blockIdx.x, bl = bh >> 2, h = bh & 3;
  int tid = threadIdx.x, wave = tid >> 6, lane = tid & 63;
  int len = lengths[b0 + bl];

  for (int i = tid; i < 224*64; i += 256) {
    int t = i >> 6, d = i & 63;
    short kv = 0, vv = 0;
    if (t < S_LEN && d < DH) {
      const short* base = QKV + ((size_t)t*CB + bl)*(3*DT) + DT + h*DH + d;
      kv = base[0];        // K
      vv = base[DT];       // V
    }
    K_lds[t][d] = kv;
    if (d < 48) VT[d][t] = vv;
  }
  __syncthreads();

  int r = lane & 15, g = lane >> 4;
  for (int mt = wave; mt < 14; mt += 4) {
    int m0 = mt*16;
    int qrow = m0 + r; if (qrow > S_LEN-1) qrow = S_LEN-1;
    const short* qp = QKV + ((size_t)qrow*CB + bl)*(3*DT) + h*DH;
    bf16x8 qf0 = *(const bf16x8*)(qp + g*8);
    bf16x8 qf1 = (g == 0) ? *(const bf16x8*)(qp + 32) : (bf16x8){0,0,0,0,0,0,0,0};
    f32x4 acc[14];
    #pragma unroll
    for (int nt = 0; nt < 14; ++nt) acc[nt] = (f32x4){0.f,0.f,0.f,0.f};
    #pragma unroll
    for (int nt = 0; nt < 14; ++nt) {
      int trow = nt*16 + r; if (trow > S_LEN-1) trow = S_LEN-1;
      bf16x8 b0 = *(const bf16x8*)&K_lds[trow][g*8];
      bf16x8 b1 = *(const bf16x8*)&K_lds[trow][32 + g*8];
      acc[nt] = __builtin_amdgcn_mfma_f32_16x16x32_bf16(qf0, b0, acc[nt], 0, 0, 0);
      acc[nt] = __builtin_amdgcn_mfma_f32_16x16x32_bf16(qf1, b1, acc[nt], 0, 0, 0);
    }
    #pragma unroll
    for (int j = 0; j < 4; ++j) {
      float mx = -3e38f;
      #pragma unroll
      for (int nt = 0; nt < 14; ++nt) {
        int t = nt*16 + r;
        float v = (t < len) ? acc[nt][j] : -1e9f;
        acc[nt][j] = v;
        mx = fmaxf(mx, v);
      }
      mx = fmaxf(mx, __shfl_xor(mx, 1));
      mx = fmaxf(mx, __shfl_xor(mx, 2));
      mx = fmaxf(mx, __shfl_xor(mx, 4));
      mx = fmaxf(mx, __shfl_xor(mx, 8));
      float sum = 0.f;
      #pragma unroll
      for (int nt = 0; nt < 14; ++nt) {
        float p = exp2f((acc[nt][j] - mx) * LOG2E);
        acc[nt][j] = p;
        sum += p;
      }
      sum += __shfl_xor(sum, 1);
      sum += __shfl_xor(sum, 2);
      sum += __shfl_xor(sum, 4);
      sum += __shfl_xor(sum, 8);
      float inv = 1.f / sum;
      #pragma unroll
      for (int nt = 0; nt < 14; ++nt)
        PT[wave][g*4 + j][nt*16 + r] = zz_bf(acc[nt][j] * inv);
    }
    f32x4 oacc0 = {0.f,0.f,0.f,0.f}, oacc1 = {0.f,0.f,0.f,0.f}, oacc2 = {0.f,0.f,0.f,0.f};
    #pragma unroll
    for (int ks = 0; ks < 7; ++ks) {
      bf16x8 pa = *(const bf16x8*)&PT[wave][r][ks*32 + g*8];
      bf16x8 v0 = *(const bf16x8*)&VT[r][ks*32 + g*8];
      bf16x8 v1 = *(const bf16x8*)&VT[16 + r][ks*32 + g*8];
      bf16x8 v2 = *(const bf16x8*)&VT[32 + r][ks*32 + g*8];
      oacc0 = __builtin_amdgcn_mfma_f32_16x16x32_bf16(pa, v0, oacc0, 0, 0, 0);
      oacc1 = __builtin_amdgcn_mfma_f32_16x16x32_bf16(pa, v1, oacc1, 0, 0, 0);
      oacc2 = __builtin_amdgcn_mfma_f32_16x16x32_bf16(pa, v2, oacc2, 0, 0, 0);
    }
    #pragma unroll
    for (int j = 0; j < 4; ++j) {
      int row = m0 + g*4 + j;
      if (row >= S_LEN) continue;
      short* op = O + ((size_t)row*CB + bl)*DT + h*DH;
      op[r] = zz_bf(oacc0[j]);
      op[16 + r] = zz_bf(oacc1[j]);
      if (32 + r < DH) op[32 + r] = zz_bf(oacc2[j]);
    }
  }
}

// ---------------- layernorm (dual write f32 + bf16) ----------------
__global__ __launch_bounds__(256) void zz_ln(const float* __restrict__ X,
    const float* __restrict__ g, const float* __restrict__ bt,
    float* __restrict__ Y, short* __restrict__ Yb, int ntok)
{
  int tok = blockIdx.x*4 + (threadIdx.x >> 6);
  if (tok >= ntok) return;
  int lane = threadIdx.x & 63;
  const float* x = X + (size_t)tok*DT;
  float v0 = x[lane], v1 = x[lane + 64];
  float v2 = (lane < 32) ? x[lane + 128] : 0.f;
  float s = v0 + v1 + v2;
  for (int off = 32; off; off >>= 1) s += __shfl_xor(s, off);
  float mean = s * (1.f/160.f);
  float d0 = v0 - mean, d1 = v1 - mean, d2 = (lane < 32) ? (v2 - mean) : 0.f;
  float q = d0*d0 + d1*d1 + d2*d2;
  for (int off = 32; off; off >>= 1) q += __shfl_xor(q, off);
  float inv = 1.f / sqrtf(q * (1.f/160.f) + 1e-5f);
  float* y = Y + (size_t)tok*DT;
  short* yb = Yb + (size_t)tok*DT;
  float o0 = d0*inv*g[lane]      + bt[lane];
  float o1 = d1*inv*g[lane + 64] + bt[lane + 64];
  y[lane]      = o0; yb[lane]      = zz_bf(o0);
  y[lane + 64] = o1; yb[lane + 64] = zz_bf(o1);
  if (lane < 32) {
    float o2 = d2*inv*g[lane + 128] + bt[lane + 128];
    y[lane + 128] = o2; yb[lane + 128] = zz_bf(o2);
  }
}

// ---------------- masked mean + feat concat ----------------
__global__ __launch_bounds__(256) void zz_agg(const float* __restrict__ XCH,
    const int* __restrict__ lengths, const float* __restrict__ emb, float* __restrict__ feat,
    int b0, int CB)
{
  int bl = blockIdx.x, tid = threadIdx.x;
  int b = b0 + bl;
  int len = lengths[b];
  if (tid < DT) {
    float acc = 0.f;
    for (int s = 0; s < len; ++s) acc += XCH[((size_t)s*CB + bl)*DT + tid];
    feat[(size_t)b*DFIN + tid] = acc / (float)(len + 1);
  } else if (tid < DFIN) {
    feat[(size_t)b*DFIN + tid] = emb[b*DI + (tid - DT)];
  }
}

// ======================================================================
extern "C" void kernel_launch(void* const* d_in, const int* in_sizes, int n_in,
                              void* d_out, int out_size, void* d_ws, size_t ws_size,
                              hipStream_t stream)
{
  (void)in_sizes; (void)n_in; (void)out_size;
  const float* src     = (const float*)d_in[0];
  const float* statc   = (const float*)d_in[1];
  const float* times   = (const float*)d_in[2];
  const int*   lengths = (const int*)  d_in[3];
  const float* R_u     = (const float*)d_in[4];
  const float* emb_w   = (const float*)d_in[5];
  const float* emb_b   = (const float*)d_in[6];
  const float* W1      = (const float*)d_in[7];
  const float* a1_s    = (const float*)d_in[8];
  const float* a1_d    = (const float*)d_in[9];
  const float* W2      = (const float*)d_in[10];
  const float* a2_s    = (const float*)d_in[11];
  const float* a2_d    = (const float*)d_in[12];
  const float* attn_in_w  = (const float*)d_in[13];
  const float* attn_in_b  = (const float*)d_in[14];
  const float* attn_out_w = (const float*)d_in[15];
  const float* attn_out_b = (const float*)d_in[16];
  const float* ff1_w = (const float*)d_in[17];
  const float* ff1_b = (const float*)d_in[18];
  const float* ff2_w = (const float*)d_in[19];
  const float* ff2_b = (const float*)d_in[20];
  const float* ln1_g = (const float*)d_in[21];
  const float* ln1_b = (const float*)d_in[22];
  const float* ln2_g = (const float*)d_in[23];
  const float* ln2_b = (const float*)d_in[24];
  const float* mlp1_w = (const float*)d_in[25];
  const float* mlp1_b = (const float*)d_in[26];
  const float* mlp2_w = (const float*)d_in[27];
  const float* mlp2_b = (const float*)d_in[28];

  // ---- small persistent buffers (floats) ----
  float* ws = (float*)d_ws;
  float* A1    = ws;                 // 663,552
  float* A2    = ws + 663552;        // 663,552
  float* SS    = ws + 1327104;       // 18,432
  float* SD    = ws + 1345536;       // 18,432
  float* SQB   = ws + 1363968;       // 512
  float* DSUM  = ws + 1364480;       // 64
  float* EMB   = ws + 1364544;       // 18,432
  float* FEAT  = ws + 1382976;       // 100,352
  float* FFEAT = ws + 1483328;       // 100,352
  float* ZEROB = ws + 1583680;       // 896 (zeroed bias)
  float* BQ    = ws + 1584576;       // 960 (scaled qkv bias)
  // bf16 weight area (shorts), 16B-aligned
  short* wb = (short*)(ws + 1585536);
  short* W1T   = wb;                 // 746,496
  short* W2T   = wb + 746496;        // 746,496
  short* WTqkv = wb + 1492992;       // 153,600
  short* WTao  = wb + 1646592;       // 51,200
  short* WTf1  = wb + 1697792;       // 40,960
  short* WTf2  = wb + 1738752;       // 40,960
  const size_t CHBASE = 1585536 + 889856;   // = 2,475,392 floats
  float* CH = ws + CHBASE;

  // ---- pick largest chunk size that fits ws_size ----
  int CB = 8;
  const int cands[7] = {512, 256, 128, 64, 32, 16, 8};
  for (int c = 0; c < 7; ++c) {
    size_t need = 4ull * (CHBASE + 168560ull * (size_t)cands[c]);
    if (need <= ws_size) { CB = cands[c]; break; }
  }
  const int NCH = NB / CB;
  const int NTOKC = S_LEN * CB;

  float* XCH   = CH;                               // 34,400*CB f32
  short* XCHb  = (short*)(CH + (size_t)34400*CB);  // 17,200*CB f-eq
  float* R0    = CH + (size_t)51600*CB;
  // GAT view
  short* Xbf   = (short*)R0;                       // 15,552*CB f-eq
  float* XPc   = R0 + (size_t)15552*CB;            // 31,104*CB f32
  short* H1bf  = (short*)(R0 + (size_t)46656*CB);  // 15,552*CB f-eq
  // transformer view (GAT bufs dead)
  short* QKVb  = (short*)R0;                       // 51,600*CB f-eq
  short* OAb   = (short*)(R0 + (size_t)51600*CB);  // 17,200*CB f-eq
  float* Tc    = R0 + (size_t)68800*CB;            // 34,400*CB f32
  short* Ybf   = (short*)(R0 + (size_t)103200*CB); // 13,760*CB f-eq

  hipMemsetAsync(DSUM, 0, 4, stream);
  hipMemsetAsync(ZEROB, 0, 896*4, stream);
  zz_emb<<<dim3(CDIV(NB*DI,256)), 256, 0, stream>>>(statc, emb_w, emb_b, EMB);
  zz_biasq<<<dim3(4), 256, 0, stream>>>(attn_in_b, BQ);

  // ---- one-time weight transpose+bf16 conversions ----
  zz_wcvt<<<dim3(CDIV(FINP*FINP,256)), 256, 0, stream>>>(W1, W1T, FIN, FIN, FINP, FINP, 0, 1.f);
  zz_wcvt<<<dim3(CDIV(FINP*FINP,256)), 256, 0, stream>>>(W2, W2T, FIN, FIN, FINP, FINP, 0, 1.f);
  for (int l = 0; l < 2; ++l) {
    zz_wcvt<<<dim3(CDIV(480*160,256)), 256, 0, stream>>>(attn_in_w + (size_t)l*DT*3*DT,
        WTqkv + (size_t)l*76800, DT, 3*DT, DT, 3*DT, DT, 0.15811388300841897f);
    zz_wcvt<<<dim3(CDIV(160*160,256)), 256, 0, stream>>>(attn_out_w + (size_t)l*DT*DT,
        WTao + (size_t)l*25600, DT, DT, DT, DT, 0, 1.f);
    zz_wcvt<<<dim3(CDIV(128*160,256)), 256, 0, stream>>>(ff1_w + (size_t)l*DT*NHID,
        WTf1 + (size_t)l*20480, DT, NHID, DT, NHID, 0, 1.f);
    zz_wcvt<<<dim3(CDIV(160*128,256)), 256, 0, stream>>>(ff2_w + (size_t)l*NHID*DT,
        WTf2 + (size_t)l*20480, NHID, DT, NHID, DT, 0, 1.f);
  }

  for (int ch = 0; ch < NCH; ++ch) {
    int b0 = ch * CB;
    // ---- GAT stack (chunk) ----
    zz_build_x<<<dim3(CDIV(CB*DI*S_LEN,256)), 256, 0, stream>>>(src, R_u, Xbf, b0, CB);
    zz_zeropad_bf<<<dim3(CDIV(CB*DI,256)), 256, 0, stream>>>(Xbf, CB);
    zz_mgemm<0,0,0><<<dim3(CDIV(CB*DI,64), 27), 256, 0, stream>>>(Xbf, W1T, ZEROB, nullptr,
        XPc, CB*DI, FINP, FINP, 1);
    zz_gat_attvec<<<dim3(DI, CB), 64, 0, stream>>>(XPc, a1_s, a1_d, SS, SD, b0);
    zz_gat_alpha<<<dim3(CB), 256, 0, stream>>>(SS, SD, (const float*)nullptr, A1, b0);
    zz_gat_apply<<<dim3(4, CB), 256, 0, stream>>>(A1, XPc, nullptr, H1bf, 0, b0, CB);
    zz_zeropad_bf<<<dim3(CDIV(CB*DI,256)), 256, 0, stream>>>(H1bf, CB);
    zz_mgemm<0,0,0><<<dim3(CDIV(CB*DI,64), 27), 256, 0, stream>>>(H1bf, W2T, ZEROB, nullptr,
        XPc, CB*DI, FINP, FINP, 1);
    zz_gat_attvec<<<dim3(DI, CB), 64, 0, stream>>>(XPc, a2_s, a2_d, SS, SD, b0);
    zz_gat_alpha<<<dim3(CB), 256, 0, stream>>>(SS, SD, A1, A2, b0);
    zz_gat_apply<<<dim3(4, CB), 256, 0, stream>>>(A2, XPc, XCH, XCHb, 1, b0, CB);
    zz_pe<<<dim3(CDIV(CB*S_LEN*16,256)), 256, 0, stream>>>(times, XCH, XCHb, b0, CB);

    // ---- transformer (chunk) ----
    for (int l = 0; l < 2; ++l) {
      zz_mgemm<0,0,1><<<dim3(CDIV(NTOKC,64), 5), 256, 0, stream>>>(XCHb,
          WTqkv + (size_t)l*76800, BQ + l*480, nullptr, QKVb, NTOKC, 3*DT, DT, 3);
      zz_fattn<<<dim3(CB*NH), 256, 0, stream>>>(QKVb, lengths, OAb, b0, CB);
      zz_mgemm<0,1,0><<<dim3(CDIV(NTOKC,64), 5), 256, 0, stream>>>(OAb,
          WTao + (size_t)l*25600, attn_out_b + l*DT, XCH, Tc, NTOKC, DT, DT, 1);
      zz_ln<<<dim3(CDIV(NTOKC,4)), 256, 0, stream>>>(Tc, ln1_g + l*DT, ln1_b + l*DT, XCH, XCHb, NTOKC);
      zz_mgemm<1,0,1><<<dim3(CDIV(NTOKC,64), 4), 256, 0, stream>>>(XCHb,
          WTf1 + (size_t)l*20480, ff1_b + l*NHID, nullptr, Ybf, NTOKC, NHID, DT, 1);
      zz_mgemm<0,1,0><<<dim3(CDIV(NTOKC,64), 5), 256, 0, stream>>>(Ybf,
          WTf2 + (size_t)l*20480, ff2_b + l*DT, XCH, Tc, NTOKC, DT, NHID, 1);
      zz_ln<<<dim3(CDIV(NTOKC,4)), 256, 0, stream>>>(Tc, ln2_g + l*DT, ln2_b + l*DT, XCH, XCHb, NTOKC);
    }

    zz_agg<<<dim3(CB), 256, 0, stream>>>(XCH, lengths, EMB, FEAT, b0, CB);
  }

  // ---- distance from alpha2 (full batch) ----
  zz_sq<<<dim3(NB), 64, 0, stream>>>(A2, SQB);
  zz_dist<<<dim3(16, 16), 256, 0, stream>>>(A2, SQB, DSUM);
  zz_dist_fin<<<1, 1, 0, stream>>>(DSUM, (float*)d_out + 1024);

  // ---- head (f32, tiny) ----
  zz_gemm<1,0><<<dim3(CDIV(DFIN,128), CDIV(NB,64)), 256, 0, stream>>>(FEAT, mlp1_w, mlp1_b,
      nullptr, FFEAT, NB, DFIN, DFIN);
  zz_gemm<0,0><<<dim3(1, CDIV(NB,64)), 256, 0, stream>>>(FFEAT, mlp2_w, mlp2_b,
      nullptr, (float*)d_out, NB, 2, DFIN);
}